// Round 8
// baseline (658.645 us; speedup 1.0000x reference)
//
#include <hip/hip_runtime.h>
#include <math.h>

// ---------------- problem constants ----------------
#define LAYERS 2
#define DMODEL 256
#define NHEAD  8
#define DHEAD  32
#define FF     512
#define KNB    9
#define MB     4
#define G1D    40
#define G2D    40
#define NTGT   2048
#define NCTX   1600          // G1D*G2D
#define RC     (MB*NCTX)     // 6400 grid rows
#define RT     (MB*NTGT)     // 8192 target rows

typedef __attribute__((ext_vector_type(8))) short short8;   // 8 bf16 (4 VGPRs)
typedef __attribute__((ext_vector_type(4))) float f32x4;    // mfma C/D

// ---------------- workspace layout (float offsets) ----------------
#define ZC_OFF    0
#define H_OFF     1638400                      // (unused; layout stability)
#define QKV_OFF   (H_OFF + 2097152)
// wT (bf16 transposed+gamma-scaled weights) in the tail of the QKV region:
// max live use of QKV region = CA kv fp32 = 3,276,800 floats.
#define WT_OFF    (QKV_OFF + 3400000)          // 1,048,576 floats of bf16 wT
#define FB_OFF    (QKV_OFF + 4500000)          // folded biases: 2*2560 floats
#define Q_OFF     (QKV_OFF + 4915200)
#define O_OFF     (Q_OFF + 2097152)
#define IDX_OFF   (O_OFF + 2097152)
#define MASK_OFF  (IDX_OFF + 73728)
#define WS_FLOATS (MASK_OFF + 73728)

// per-layer wT offsets (shorts)
#define WT_LAYER   1048576
#define WT_QKV     0
#define WT_WO      196608
#define WT_W1      262144
#define WT_W2      393216
#define WT_CWQ     524288
#define WT_CWKV    589824
#define WT_CWO     720896
#define WT_CW1     786432
#define WT_CW2     917504
// per-layer folded-bias offsets (floats), layer stride 2560
#define FB_LAYER   2560
#define FB_QKV     0
#define FB_W1      768
#define FB_WKV     1280
#define FB_WQ      1792
#define FB_CW1     2048

static __device__ __forceinline__ float gelu_f(float x){
  float t = tanhf(0.7978845608028654f * (x + 0.044715f * x * x * x));
  return 0.5f * x * (1.0f + t);
}
static __device__ __forceinline__ unsigned int bf16_rne(float x){
  unsigned int u = __float_as_uint(x);
  return (u + 0x7fffu + ((u >> 16) & 1u)) >> 16;
}
static __device__ __forceinline__ unsigned int pack_bf16x2(float lo, float hi){
  return bf16_rne(lo) | (bf16_rne(hi) << 16);
}

// ---------------- weight prep: fp32 [K][N] -> bf16 [N][K], row-scaled by gamma -------
struct TDesc { const float* src; const float* gamma; int dstoff; int K; int N; };
struct TTable { TDesc e[18]; };

__global__ __launch_bounds__(256)
void wprep_kernel(TTable t, unsigned short* __restrict__ wt){
  TDesc d = t.e[blockIdx.z];
  int n0 = blockIdx.x * 32, k0 = blockIdx.y * 32;
  if (n0 >= d.N || k0 >= d.K) return;
  __shared__ float tile[32][33];
  int tx = threadIdx.x, ty = threadIdx.y;
  #pragma unroll
  for (int j = 0; j < 4; j++){
    int k = k0 + ty * 4 + j;
    float v = d.src[(size_t)k * d.N + n0 + tx];
    if (d.gamma) v *= d.gamma[k];
    tile[ty * 4 + j][tx] = v;
  }
  __syncthreads();
  #pragma unroll
  for (int j = 0; j < 4; j++)
    wt[(size_t)d.dstoff + (size_t)(n0 + ty * 4 + j) * d.K + k0 + tx] =
        (unsigned short)bf16_rne(tile[tx][ty * 4 + j]);
}

// ---------------- bias fold: fb[n] = base[n] + sum_k beta[k]*W[k][n] ----------------
struct BDesc { const float* W; const float* beta; const float* base; int outoff; int N; };
struct BTable { BDesc e[10]; };

__global__ __launch_bounds__(256)
void bfold_kernel(BTable t, float* __restrict__ fb){
  BDesc d = t.e[blockIdx.x];
  for (int n = threadIdx.x; n < d.N; n += 256){
    float s = d.base ? d.base[n] : 0.f;
    for (int k = 0; k < 256; k++) s += d.beta[k] * d.W[(size_t)k * d.N + n];
    fb[d.outoff + n] = s;
  }
}

// ---------------- nearest-grid-neighbour index/mask precompute ----------------
__global__ void nn_idx_kernel(const float* __restrict__ xc, const float* __restrict__ xt,
                              int* __restrict__ idx, float* __restrict__ mask){
  int g = blockIdx.x * blockDim.x + threadIdx.x;
  if (g >= MB * NTGT) return;
  int m = g >> 11;
  float x0 = xt[(size_t)g * 2 + 0];
  float x1 = xt[(size_t)g * 2 + 1];
  const float* xcm = xc + (size_t)m * G1D * G2D * 2;
  int n0 = 0; float b0 = 1e30f;
  for (int i = 0; i < G1D; i++){
    float d = fabsf(x0 - xcm[i * (G2D * 2)]);
    if (d < b0){ b0 = d; n0 = i; }
  }
  int n1 = 0; float b1 = 1e30f;
  for (int j = 0; j < G2D; j++){
    float d = fabsf(x1 - xcm[j * 2 + 1]);
    if (d < b1){ b1 = d; n1 = j; }
  }
  #pragma unroll
  for (int a = 0; a < 3; a++){
    int r0 = n0 + a - 1;
    bool v0 = (r0 >= 0) && (r0 < G1D);
    int i0 = min(max(r0, 0), G1D - 1);
    #pragma unroll
    for (int b = 0; b < 3; b++){
      int r1 = n1 + b - 1;
      bool v1 = (r1 >= 0) && (r1 < G2D);
      int i1 = min(max(r1, 0), G2D - 1);
      idx [(size_t)g * KNB + a * 3 + b] = i0 * G2D + i1;
      mask[(size_t)g * KNB + a * 3 + b] = (v0 && v1) ? 1.0f : 0.0f;
    }
  }
}

// ================= single-stage full-K MFMA GEMM (block 128x128, 4 waves 2x2) =======
// LDS stride 264 shorts (132 dwords == 4 mod 8) -> all b128 frag reads/writes uniform
// 8 dwords/bank = conflict-free. One barrier per K-chunk of 256.
#define LSTR 264
// flags: 1=bias, 2=gelu, 4=residual(fp32), 8=bf16 out

static __device__ __forceinline__ void gemm_core(
    const unsigned short* Als, const unsigned short* Bls, f32x4 acc[4][4],
    int wm, int wn, int l16, int grp){
  const unsigned short* Ab = Als + (wm * 64 + l16) * LSTR + grp * 8;
  const unsigned short* Bb = Bls + (wn * 64 + l16) * LSTR + grp * 8;
  #pragma unroll
  for (int kk = 0; kk < 8; kk++){
    short8 af[4], bf[4];
    #pragma unroll
    for (int m = 0; m < 4; m++) af[m] = *(const short8*)(Ab + m * 16 * LSTR + kk * 32);
    #pragma unroll
    for (int n = 0; n < 4; n++) bf[n] = *(const short8*)(Bb + n * 16 * LSTR + kk * 32);
    #pragma unroll
    for (int m = 0; m < 4; m++)
      #pragma unroll
      for (int n = 0; n < 4; n++)
        acc[m][n] = __builtin_amdgcn_mfma_f32_16x16x32_bf16(af[m], bf[n], acc[m][n], 0, 0, 0);
  }
}

static __device__ __forceinline__ void gemm_epilogue(
    f32x4 acc[4][4], const float* bias, const float* res, void* C,
    int r0, int c0, int N, int flags, int wm, int wn, int l16, int grp){
  #pragma unroll
  for (int n = 0; n < 4; n++){
    int gc = c0 + wn * 64 + n * 16 + l16;
    float bv = (flags & 1) ? bias[gc] : 0.f;
    #pragma unroll
    for (int m = 0; m < 4; m++){
      int grb = r0 + wm * 64 + m * 16 + grp * 4;
      #pragma unroll
      for (int r = 0; r < 4; r++){
        float v = acc[m][n][r] + bv;
        if (flags & 2) v = gelu_f(v);
        if (flags & 4) v += res[(size_t)(grb + r) * N + gc];
        if (flags & 8) ((unsigned short*)C)[(size_t)(grb + r) * N + gc] = (unsigned short)bf16_rne(v);
        else           ((float*)C)[(size_t)(grb + r) * N + gc] = v;
      }
    }
  }
}

// --- GEMM with fused LayerNorm-normalize on A (X fp32 [R][256], affine folded into Wt/bias)
__global__ __launch_bounds__(256)
void gemm_ln(const float* __restrict__ X, const unsigned short* __restrict__ Wt,
             const float* __restrict__ bias, void* __restrict__ C, int N, int flags){
  __shared__ unsigned short Als[128 * LSTR];
  __shared__ unsigned short Bls[128 * LSTR];
  int tid = threadIdx.x;
  int r0 = blockIdx.y * 128, c0 = blockIdx.x * 128;

  // stage B: 128 cols x 256 k ; 2 threads/col, 128 shorts (16 x uint4) each
  {
    int col = tid >> 1, half = tid & 1;
    const unsigned short* bp = Wt + (size_t)(c0 + col) * 256 + half * 128;
    #pragma unroll
    for (int j = 0; j < 16; j++)
      *(uint4*)&Bls[col * LSTR + half * 128 + j * 8] = *(const uint4*)(bp + j * 8);
  }
  // stage A with LN-normalize: 2 passes x 64 rows, 4 threads/row (64 f32 each)
  int lr = tid >> 2, qt = tid & 3;
  for (int p = 0; p < 2; p++){
    int row = p * 64 + lr;
    const float* xp = X + (size_t)(r0 + row) * 256 + qt * 64;
    float4 xv[16];
    float s = 0.f, ss = 0.f;
    #pragma unroll
    for (int j = 0; j < 16; j++){
      xv[j] = *(const float4*)(xp + j * 4);
      s  += xv[j].x + xv[j].y + xv[j].z + xv[j].w;
      ss += xv[j].x*xv[j].x + xv[j].y*xv[j].y + xv[j].z*xv[j].z + xv[j].w*xv[j].w;
    }
    s  += __shfl_xor(s, 1);  s  += __shfl_xor(s, 2);
    ss += __shfl_xor(ss, 1); ss += __shfl_xor(ss, 2);
    float mu = s * (1.f / 256.f);
    float rs = rsqrtf(ss * (1.f / 256.f) - mu * mu + 1e-5f);
    #pragma unroll
    for (int j = 0; j < 16; j += 2){
      uint4 w;
      w.x = pack_bf16x2((xv[j].x - mu) * rs,   (xv[j].y - mu) * rs);
      w.y = pack_bf16x2((xv[j].z - mu) * rs,   (xv[j].w - mu) * rs);
      w.z = pack_bf16x2((xv[j+1].x - mu) * rs, (xv[j+1].y - mu) * rs);
      w.w = pack_bf16x2((xv[j+1].z - mu) * rs, (xv[j+1].w - mu) * rs);
      *(uint4*)&Als[row * LSTR + qt * 64 + j * 4] = w;
    }
  }
  __syncthreads();

  int wave = tid >> 6, lane = tid & 63;
  int wm = wave >> 1, wn = wave & 1;
  int l16 = lane & 15, grp = lane >> 4;
  f32x4 acc[4][4];
  #pragma unroll
  for (int m = 0; m < 4; m++)
    #pragma unroll
    for (int n = 0; n < 4; n++) acc[m][n] = (f32x4){0.f, 0.f, 0.f, 0.f};
  gemm_core(Als, Bls, acc, wm, wn, l16, grp);
  gemm_epilogue(acc, bias, nullptr, C, r0, c0, N, flags, wm, wn, l16, grp);
}

// --- GEMM with bf16 A [R][K], K in {256, 512} (chunked) ---
__global__ __launch_bounds__(256)
void gemm_bf(const unsigned short* __restrict__ A, const unsigned short* __restrict__ Wt,
             const float* __restrict__ bias, const float* __restrict__ res,
             void* __restrict__ C, int K, int N, int flags){
  __shared__ unsigned short Als[128 * LSTR];
  __shared__ unsigned short Bls[128 * LSTR];
  int tid = threadIdx.x;
  int r0 = blockIdx.y * 128, c0 = blockIdx.x * 128;
  int row = tid >> 1, half = tid & 1;

  int wave = tid >> 6, lane = tid & 63;
  int wm = wave >> 1, wn = wave & 1;
  int l16 = lane & 15, grp = lane >> 4;
  f32x4 acc[4][4];
  #pragma unroll
  for (int m = 0; m < 4; m++)
    #pragma unroll
    for (int n = 0; n < 4; n++) acc[m][n] = (f32x4){0.f, 0.f, 0.f, 0.f};

  int chunks = K >> 8;
  for (int ch = 0; ch < chunks; ch++){
    if (ch) __syncthreads();   // readers done before overwrite
    const unsigned short* ap = A  + (size_t)(r0 + row) * K + ch * 256 + half * 128;
    const unsigned short* bp = Wt + (size_t)(c0 + row) * K + ch * 256 + half * 128;
    #pragma unroll
    for (int j = 0; j < 16; j++){
      *(uint4*)&Als[row * LSTR + half * 128 + j * 8] = *(const uint4*)(ap + j * 8);
      *(uint4*)&Bls[row * LSTR + half * 128 + j * 8] = *(const uint4*)(bp + j * 8);
    }
    __syncthreads();
    gemm_core(Als, Bls, acc, wm, wn, l16, grp);
  }
  gemm_epilogue(acc, bias, res, C, r0, c0, N, flags, wm, wn, l16, grp);
}

// ---------------- self-attention: bf16 MFMA flash (exact r4 code, 56us measured) ----
#define KSTR 40
#define VSTR 72
#define PSTR 72
__global__ __launch_bounds__(256)
void sa_attn_mfma(const unsigned short* __restrict__ qkv, unsigned short* __restrict__ ob){
  int m = blockIdx.z, h = blockIdx.y;
  int tid  = threadIdx.x;
  int wave = tid >> 6, lane = tid & 63;
  int qr = lane & 15, grp = lane >> 4;
  int q0 = blockIdx.x * 64 + wave * 16;

  __shared__ unsigned short Kls[2][64 * KSTR];
  __shared__ unsigned short Vls[2][32 * VSTR];
  __shared__ unsigned short Pls[4][16 * PSTR];
  unsigned short* Pw = Pls[wave];

  const float scale = 0.17677669529663687f;

  short8 qf = *(const short8*)(qkv + ((size_t)(m * NCTX + q0 + qr)) * 768 + h * 32 + grp * 8);

  int skey = tid >> 2;
  int scol = (tid & 3) * 8;
  const unsigned short* kbase = qkv + (size_t)m * NCTX * 768 + 256 + h * 32 + scol;

  uint4 kreg = *(const uint4*)(kbase + (size_t)skey * 768);
  uint4 vreg = *(const uint4*)(kbase + (size_t)skey * 768 + 256);

  float mq = -1e30f, lq = 0.0f;
  f32x4 acc0 = {0.f, 0.f, 0.f, 0.f};
  f32x4 acc1 = {0.f, 0.f, 0.f, 0.f};

  {
    *(uint4*)&Kls[0][skey * KSTR + scol] = kreg;
    unsigned int vv[4] = {vreg.x, vreg.y, vreg.z, vreg.w};
    #pragma unroll
    for (int j = 0; j < 4; j++){
      Vls[0][(scol + 2 * j    ) * VSTR + skey] = (unsigned short)(vv[j] & 0xffffu);
      Vls[0][(scol + 2 * j + 1) * VSTR + skey] = (unsigned short)(vv[j] >> 16);
    }
  }

  for (int kt = 0; kt < NCTX / 64; kt++){
    int b = kt & 1;
    __syncthreads();
    if (kt + 1 < NCTX / 64){
      kreg = *(const uint4*)(kbase + (size_t)((kt + 1) * 64 + skey) * 768);
      vreg = *(const uint4*)(kbase + (size_t)((kt + 1) * 64 + skey) * 768 + 256);
    }

    f32x4 s0 = {0.f,0.f,0.f,0.f}, s1 = {0.f,0.f,0.f,0.f};
    f32x4 s2 = {0.f,0.f,0.f,0.f}, s3 = {0.f,0.f,0.f,0.f};
    {
      const short8 k0 = *(const short8*)&Kls[b][( 0 + qr) * KSTR + grp * 8];
      const short8 k1 = *(const short8*)&Kls[b][(16 + qr) * KSTR + grp * 8];
      const short8 k2 = *(const short8*)&Kls[b][(32 + qr) * KSTR + grp * 8];
      const short8 k3 = *(const short8*)&Kls[b][(48 + qr) * KSTR + grp * 8];
      s0 = __builtin_amdgcn_mfma_f32_16x16x32_bf16(k0, qf, s0, 0, 0, 0);
      s1 = __builtin_amdgcn_mfma_f32_16x16x32_bf16(k1, qf, s1, 0, 0, 0);
      s2 = __builtin_amdgcn_mfma_f32_16x16x32_bf16(k2, qf, s2, 0, 0, 0);
      s3 = __builtin_amdgcn_mfma_f32_16x16x32_bf16(k3, qf, s3, 0, 0, 0);
    }

    float sc[4][4];
    #pragma unroll
    for (int r = 0; r < 4; r++){
      sc[0][r] = s0[r] * scale; sc[1][r] = s1[r] * scale;
      sc[2][r] = s2[r] * scale; sc[3][r] = s3[r] * scale;
    }
    float tm = sc[0][0];
    #pragma unroll
    for (int kb = 0; kb < 4; kb++)
      #pragma unroll
      for (int r = 0; r < 4; r++) tm = fmaxf(tm, sc[kb][r]);
    tm = fmaxf(tm, __shfl_xor(tm, 16));
    tm = fmaxf(tm, __shfl_xor(tm, 32));
    float mn = fmaxf(mq, tm);
    float corr = __expf(mq - mn);
    float ts = 0.f;
    float p[4][4];
    #pragma unroll
    for (int kb = 0; kb < 4; kb++)
      #pragma unroll
      for (int r = 0; r < 4; r++){
        float pv = __expf(sc[kb][r] - mn);
        p[kb][r] = pv; ts += pv;
      }
    ts += __shfl_xor(ts, 16);
    ts += __shfl_xor(ts, 32);
    lq = lq * corr + ts;
    mq = mn;
    #pragma unroll
    for (int r = 0; r < 4; r++){ acc0[r] *= corr; acc1[r] *= corr; }

    #pragma unroll
    for (int kb = 0; kb < 4; kb++){
      *(unsigned int*)&Pw[qr * PSTR + kb * 16 + grp * 4]     = pack_bf16x2(p[kb][0], p[kb][1]);
      *(unsigned int*)&Pw[qr * PSTR + kb * 16 + grp * 4 + 2] = pack_bf16x2(p[kb][2], p[kb][3]);
    }

    #pragma unroll
    for (int hh = 0; hh < 2; hh++){
      const short8 pf = *(const short8*)&Pw[qr * PSTR + hh * 32 + grp * 8];
      const short8 v0 = *(const short8*)&Vls[b][( 0 + qr) * VSTR + hh * 32 + grp * 8];
      const short8 v1 = *(const short8*)&Vls[b][(16 + qr) * VSTR + hh * 32 + grp * 8];
      acc0 = __builtin_amdgcn_mfma_f32_16x16x32_bf16(v0, pf, acc0, 0, 0, 0);
      acc1 = __builtin_amdgcn_mfma_f32_16x16x32_bf16(v1, pf, acc1, 0, 0, 0);
    }

    if (kt + 1 < NCTX / 64){
      *(uint4*)&Kls[b ^ 1][skey * KSTR + scol] = kreg;
      unsigned int vv[4] = {vreg.x, vreg.y, vreg.z, vreg.w};
      #pragma unroll
      for (int j = 0; j < 4; j++){
        Vls[b ^ 1][(scol + 2 * j    ) * VSTR + skey] = (unsigned short)(vv[j] & 0xffffu);
        Vls[b ^ 1][(scol + 2 * j + 1) * VSTR + skey] = (unsigned short)(vv[j] >> 16);
      }
    }
  }

  float inv = 1.0f / lq;
  unsigned short* op = ob + ((size_t)(m * NCTX + q0 + qr)) * DMODEL + h * DHEAD;
  uint2 o16a, o16b;
  o16a.x = pack_bf16x2(acc0[0] * inv, acc0[1] * inv);
  o16a.y = pack_bf16x2(acc0[2] * inv, acc0[3] * inv);
  o16b.x = pack_bf16x2(acc1[0] * inv, acc1[1] * inv);
  o16b.y = pack_bf16x2(acc1[2] * inv, acc1[3] * inv);
  *(uint2*)(op + grp * 4)      = o16a;
  *(uint2*)(op + 16 + grp * 4) = o16b;
}

// ---------------- cross-attention over 9 gathered neighbours (bf16 out) -----------
__global__ __launch_bounds__(256)
void ca_attn_kernel(const float* __restrict__ qb, const float* __restrict__ kv,
                    const int* __restrict__ idx, const float* __restrict__ mask,
                    unsigned short* __restrict__ ob){
  int g = blockIdx.x;
  int m = g >> 11;
  int tid = threadIdx.x;
  const float scale = 0.17677669529663687f;
  float q = qb[(size_t)g * DMODEL + tid] * scale;
  float s[KNB];
  int rws[KNB];
  #pragma unroll
  for (int k = 0; k < KNB; k++){
    int row = idx[(size_t)g * KNB + k];
    rws[k] = row;
    float p = q * kv[((size_t)(m * NCTX + row)) * 512 + tid];
    #pragma unroll
    for (int off = 16; off > 0; off >>= 1) p += __shfl_xor(p, off, 32);
    s[k] = (mask[(size_t)g * KNB + k] > 0.5f) ? p : -1e30f;
  }
  float sm = s[0];
  #pragma unroll
  for (int k = 1; k < KNB; k++) sm = fmaxf(sm, s[k]);
  float den = 0.f, w[KNB];
  #pragma unroll
  for (int k = 0; k < KNB; k++){ w[k] = __expf(s[k] - sm); den += w[k]; }
  float inv = 1.0f / den;
  float o = 0.f;
  #pragma unroll
  for (int k = 0; k < KNB; k++)
    o += w[k] * kv[((size_t)(m * NCTX + rws[k])) * 512 + 256 + tid];
  ob[(size_t)g * DMODEL + tid] = (unsigned short)bf16_rne(o * inv);
}

// ---------------- host launcher ----------------
extern "C" void kernel_launch(void* const* d_in, const int* in_sizes, int n_in,
                              void* d_out, int out_size, void* d_ws, size_t ws_size,
                              hipStream_t stream){
  const float* xc      = (const float*)d_in[0];
  const float* zc_in   = (const float*)d_in[1];
  const float* xt      = (const float*)d_in[2];
  const float* zt_in   = (const float*)d_in[3];
  const float* sa_wqkv = (const float*)d_in[4];
  const float* sa_wo   = (const float*)d_in[5];
  const float* sa_ln1  = (const float*)d_in[6];
  const float* sa_ln2  = (const float*)d_in[7];
  const float* sa_w1   = (const float*)d_in[8];
  const float* sa_b1   = (const float*)d_in[9];
  const float* sa_w2   = (const float*)d_in[10];
  const float* sa_b2   = (const float*)d_in[11];
  const float* ca_wq   = (const float*)d_in[12];
  const float* ca_wkv  = (const float*)d_in[13];
  const float* ca_wo   = (const float*)d_in[14];
  const float* ca_lnq  = (const float*)d_in[15];
  const float* ca_lnkv = (const float*)d_in[16];
  const float* ca_ln2  = (const float*)d_in[17];
  const float* ca_w1   = (const float*)d_in[18];
  const float* ca_b1   = (const float*)d_in[19];
  const float* ca_w2   = (const float*)d_in[20];
  const float* ca_b2   = (const float*)d_in[21];

  if (ws_size < (size_t)WS_FLOATS * sizeof(float)) return;
  float* ws    = (float*)d_ws;
  float* zc    = ws + ZC_OFF;
  float* qkvb  = ws + QKV_OFF;   // aliased: bf16 qkv / fp32 CA kv / bf16 ffn-mid
  unsigned short* qkv16 = (unsigned short*)qkvb;
  unsigned short* wt    = (unsigned short*)(ws + WT_OFF);
  float* fb    = ws + FB_OFF;
  float* qb    = ws + Q_OFF;
  unsigned short* ob16 = (unsigned short*)(ws + O_OFF);
  int*   idxb  = (int*)(ws + IDX_OFF);
  float* maskb = ws + MASK_OFF;
  float* zt    = (float*)d_out;

  // ---- weight prep (transpose + gamma row-scale) ----
  TTable tt;
  for (int l = 0; l < LAYERS; l++){
    int b = l * WT_LAYER, i = l * 9;
    const float* g_ln1  = sa_ln1  + l * 512;
    const float* g_ln2  = sa_ln2  + l * 512;
    const float* g_lnq  = ca_lnq  + l * 512;
    const float* g_lnkv = ca_lnkv + l * 512;
    const float* g_cln2 = ca_ln2  + l * 512;
    tt.e[i + 0] = { sa_wqkv + (size_t)l * 256 * 768, g_ln1,  b + WT_QKV,  256, 768 };
    tt.e[i + 1] = { sa_wo   + (size_t)l * 256 * 256, nullptr, b + WT_WO,  256, 256 };
    tt.e[i + 2] = { sa_w1   + (size_t)l * 256 * 512, g_ln2,  b + WT_W1,   256, 512 };
    tt.e[i + 3] = { sa_w2   + (size_t)l * 512 * 256, nullptr, b + WT_W2,  512, 256 };
    tt.e[i + 4] = { ca_wq   + (size_t)l * 256 * 256, g_lnq,  b + WT_CWQ,  256, 256 };
    tt.e[i + 5] = { ca_wkv  + (size_t)l * 256 * 512, g_lnkv, b + WT_CWKV, 256, 512 };
    tt.e[i + 6] = { ca_wo   + (size_t)l * 256 * 256, nullptr, b + WT_CWO, 256, 256 };
    tt.e[i + 7] = { ca_w1   + (size_t)l * 256 * 512, g_cln2, b + WT_CW1,  256, 512 };
    tt.e[i + 8] = { ca_w2   + (size_t)l * 512 * 256, nullptr, b + WT_CW2, 512, 256 };
  }
  wprep_kernel<<<dim3(24, 16, 18), dim3(32, 8), 0, stream>>>(tt, wt);

  // ---- beta fold into biases ----
  BTable bt;
  for (int l = 0; l < LAYERS; l++){
    int fo = l * FB_LAYER, i = l * 5;
    bt.e[i + 0] = { sa_wqkv + (size_t)l * 256 * 768, sa_ln1  + l * 512 + 256, nullptr,        fo + FB_QKV, 768 };
    bt.e[i + 1] = { sa_w1   + (size_t)l * 256 * 512, sa_ln2  + l * 512 + 256, sa_b1 + l * FF, fo + FB_W1,  512 };
    bt.e[i + 2] = { ca_wkv  + (size_t)l * 256 * 512, ca_lnkv + l * 512 + 256, nullptr,        fo + FB_WKV, 512 };
    bt.e[i + 3] = { ca_wq   + (size_t)l * 256 * 256, ca_lnq  + l * 512 + 256, nullptr,        fo + FB_WQ,  256 };
    bt.e[i + 4] = { ca_w1   + (size_t)l * 256 * 512, ca_ln2  + l * 512 + 256, ca_b1 + l * FF, fo + FB_CW1, 512 };
  }
  bfold_kernel<<<10, 256, 0, stream>>>(bt, fb);

  nn_idx_kernel<<<(MB * NTGT) / 256, 256, 0, stream>>>(xc, xt, idxb, maskb);

  for (int l = 0; l < LAYERS; l++){
    const unsigned short* wl = wt + (size_t)l * WT_LAYER;
    const float* fl = fb + (size_t)l * FB_LAYER;
    const float* zc_src = (l == 0) ? zc_in : zc;
    const float* zt_src = (l == 0) ? zt_in : zt;

    // ---------- self-attention block on zc ----------
    gemm_ln<<<dim3(768/128, RC/128), 256, 0, stream>>>(
        zc_src, wl + WT_QKV, fl + FB_QKV, qkv16, 768, 1 | 8);
    sa_attn_mfma<<<dim3(NCTX / 64, NHEAD, MB), 256, 0, stream>>>(qkv16, ob16);
    gemm_bf<<<dim3(256/128, RC/128), 256, 0, stream>>>(
        ob16, wl + WT_WO, nullptr, zc_src, zc, 256, 256, 4);
    gemm_ln<<<dim3(512/128, RC/128), 256, 0, stream>>>(
        zc, wl + WT_W1, fl + FB_W1, qkv16, 512, 1 | 2 | 8);
    gemm_bf<<<dim3(256/128, RC/128), 256, 0, stream>>>(
        qkv16, wl + WT_W2, sa_b2 + l * DMODEL, zc, zc, 512, 256, 1 | 4);

    // ---------- cross-attention block on zt ----------
    gemm_ln<<<dim3(512/128, RC/128), 256, 0, stream>>>(
        zc, wl + WT_CWKV, fl + FB_WKV, qkvb, 512, 1);
    gemm_ln<<<dim3(256/128, RT/128), 256, 0, stream>>>(
        zt_src, wl + WT_CWQ, fl + FB_WQ, qb, 256, 1);
    ca_attn_kernel<<<RT, 256, 0, stream>>>(qb, qkvb, idxb, maskb, ob16);
    gemm_bf<<<dim3(256/128, RT/128), 256, 0, stream>>>(
        ob16, wl + WT_CWO, nullptr, zt_src, zt, 256, 256, 4);
    gemm_ln<<<dim3(512/128, RT/128), 256, 0, stream>>>(
        zt, wl + WT_CW1, fl + FB_CW1, qkv16, 512, 1 | 2 | 8);
    gemm_bf<<<dim3(256/128, RT/128), 256, 0, stream>>>(
        qkv16, wl + WT_CW2, ca_b2 + l * DMODEL, zt, zt, 512, 256, 1 | 4);
  }
}

// Round 9
// 546.468 us; speedup vs baseline: 1.2053x; 1.2053x over previous
//
#include <hip/hip_runtime.h>
#include <math.h>

// ---------------- problem constants ----------------
#define LAYERS 2
#define DMODEL 256
#define NHEAD  8
#define DHEAD  32
#define FF     512
#define KNB    9
#define MB     4
#define G1D    40
#define G2D    40
#define NTGT   2048
#define NCTX   1600          // G1D*G2D
#define RC     (MB*NCTX)     // 6400 grid rows
#define RT     (MB*NTGT)     // 8192 target rows

typedef __attribute__((ext_vector_type(8))) short short8;   // 8 bf16 (4 VGPRs)
typedef __attribute__((ext_vector_type(4))) float f32x4;    // mfma C/D

// ---------------- workspace layout (float offsets) ----------------
#define ZC_OFF    0
#define H_OFF     1638400                      // bf16 LN output (RT*256 shorts fits)
#define QKV_OFF   (H_OFF + 2097152)
// wT tail of QKV region: max live use of QKV region = CA kv fp32 = 3,276,800 floats.
#define WT_OFF    (QKV_OFF + 3400000)          // 1,048,576 floats of bf16 wT
#define FB_OFF    (QKV_OFF + 4500000)          // folded biases: 2*2560 floats
#define Q_OFF     (QKV_OFF + 4915200)
#define O_OFF     (Q_OFF + 2097152)
#define IDX_OFF   (O_OFF + 2097152)
#define MASK_OFF  (IDX_OFF + 73728)
#define WS_FLOATS (MASK_OFF + 73728)

// per-layer wT offsets (shorts)
#define WT_LAYER   1048576
#define WT_QKV     0
#define WT_WO      196608
#define WT_W1      262144
#define WT_W2      393216
#define WT_CWQ     524288
#define WT_CWKV    589824
#define WT_CWO     720896
#define WT_CW1     786432
#define WT_CW2     917504
// per-layer folded-bias offsets (floats), layer stride 2560
#define FB_LAYER   2560
#define FB_QKV     0
#define FB_W1      768
#define FB_WKV     1280
#define FB_WQ      1792
#define FB_CW1     2048

static __device__ __forceinline__ float gelu_f(float x){
  float t = tanhf(0.7978845608028654f * (x + 0.044715f * x * x * x));
  return 0.5f * x * (1.0f + t);
}
static __device__ __forceinline__ unsigned int bf16_rne(float x){
  unsigned int u = __float_as_uint(x);
  return (u + 0x7fffu + ((u >> 16) & 1u)) >> 16;
}
static __device__ __forceinline__ unsigned int pack_bf16x2(float lo, float hi){
  return bf16_rne(lo) | (bf16_rne(hi) << 16);
}

// ---------------- weight prep: fp32 [K][N] -> bf16 [N][K], row-scaled by gamma -------
struct TDesc { const float* src; const float* gamma; int dstoff; int K; int N; };
struct TTable { TDesc e[18]; };

__global__ __launch_bounds__(256)
void wprep_kernel(TTable t, unsigned short* __restrict__ wt){
  TDesc d = t.e[blockIdx.z];
  int n0 = blockIdx.x * 32, k0 = blockIdx.y * 32;
  if (n0 >= d.N || k0 >= d.K) return;
  __shared__ float tile[32][33];
  int tx = threadIdx.x, ty = threadIdx.y;
  #pragma unroll
  for (int j = 0; j < 4; j++){
    int k = k0 + ty * 4 + j;
    float v = d.src[(size_t)k * d.N + n0 + tx];
    if (d.gamma) v *= d.gamma[k];
    tile[ty * 4 + j][tx] = v;
  }
  __syncthreads();
  #pragma unroll
  for (int j = 0; j < 4; j++)
    wt[(size_t)d.dstoff + (size_t)(n0 + ty * 4 + j) * d.K + k0 + tx] =
        (unsigned short)bf16_rne(tile[tx][ty * 4 + j]);
}

// ---------------- bias fold (parallel): fb[n] = base[n] + sum_k beta[k]*W[k][n] ------
struct BDesc { const float* W; const float* beta; const float* base; int outoff; int N; };
struct BTable { BDesc e[10]; };

__global__ __launch_bounds__(256)
void bfold_kernel(BTable t, float* __restrict__ fb){
  BDesc d = t.e[blockIdx.x];
  int n = blockIdx.y * 64 + (threadIdx.x >> 2);
  int q = threadIdx.x & 3;
  if (n >= d.N) return;
  float s = 0.f;
  #pragma unroll 4
  for (int k = q * 64; k < q * 64 + 64; k++)
    s += d.beta[k] * d.W[(size_t)k * d.N + n];
  s += __shfl_xor(s, 1);
  s += __shfl_xor(s, 2);
  if (q == 0) fb[d.outoff + n] = s + (d.base ? d.base[n] : 0.f);
}

// ---------------- nearest-grid-neighbour index/mask precompute ----------------
__global__ void nn_idx_kernel(const float* __restrict__ xc, const float* __restrict__ xt,
                              int* __restrict__ idx, float* __restrict__ mask){
  int g = blockIdx.x * blockDim.x + threadIdx.x;
  if (g >= MB * NTGT) return;
  int m = g >> 11;
  float x0 = xt[(size_t)g * 2 + 0];
  float x1 = xt[(size_t)g * 2 + 1];
  const float* xcm = xc + (size_t)m * G1D * G2D * 2;
  int n0 = 0; float b0 = 1e30f;
  for (int i = 0; i < G1D; i++){
    float d = fabsf(x0 - xcm[i * (G2D * 2)]);
    if (d < b0){ b0 = d; n0 = i; }
  }
  int n1 = 0; float b1 = 1e30f;
  for (int j = 0; j < G2D; j++){
    float d = fabsf(x1 - xcm[j * 2 + 1]);
    if (d < b1){ b1 = d; n1 = j; }
  }
  #pragma unroll
  for (int a = 0; a < 3; a++){
    int r0 = n0 + a - 1;
    bool v0 = (r0 >= 0) && (r0 < G1D);
    int i0 = min(max(r0, 0), G1D - 1);
    #pragma unroll
    for (int b = 0; b < 3; b++){
      int r1 = n1 + b - 1;
      bool v1 = (r1 >= 0) && (r1 < G2D);
      int i1 = min(max(r1, 0), G2D - 1);
      idx [(size_t)g * KNB + a * 3 + b] = i0 * G2D + i1;
      mask[(size_t)g * KNB + a * 3 + b] = (v0 && v1) ? 1.0f : 0.0f;
    }
  }
}

// ---------------- LayerNorm normalize-only (affine folded into wT/bias), bf16 out ----
__global__ __launch_bounds__(256)
void ln_norm(const float* __restrict__ x, unsigned short* __restrict__ y, int rows){
  int gw   = blockIdx.x * 4 + (threadIdx.x >> 6);
  int lane = threadIdx.x & 63;
  if (gw >= rows) return;
  const float* xr = x + (size_t)gw * DMODEL;
  int d0 = lane * 4;
  float4 xv = *(const float4*)(xr + d0);
  float s = xv.x + xv.y + xv.z + xv.w;
  #pragma unroll
  for (int off = 32; off > 0; off >>= 1) s += __shfl_xor(s, off);
  float mu = s * (1.0f / DMODEL);
  float dx0 = xv.x - mu, dx1 = xv.y - mu, dx2 = xv.z - mu, dx3 = xv.w - mu;
  float v = dx0*dx0 + dx1*dx1 + dx2*dx2 + dx3*dx3;
  #pragma unroll
  for (int off = 32; off > 0; off >>= 1) v += __shfl_xor(v, off);
  float rs = rsqrtf(v * (1.0f / DMODEL) + 1e-5f);
  uint2 w;
  w.x = pack_bf16x2(dx0 * rs, dx1 * rs);
  w.y = pack_bf16x2(dx2 * rs, dx3 * rs);
  *(uint2*)(y + (size_t)gw * DMODEL + d0) = w;
}

// ================= MFMA GEMM: 128x128 tile, BK=64 dbuf, global_load_lds staging =====
// A bf16 [R][K], Wt bf16 [N][K]. LDS linear [128][64] shorts per buffer (16KB each),
// XOR-swizzled on SOURCE at stage time and on ds_read (rule #21: linear dest +
// inverse-swz source + swz read; XOR is its own inverse). 64KB LDS -> 2 blocks/CU.
// flags: 1=bias, 2=gelu, 4=residual(fp32), 8=bf16 out

// stage one 128x64-short chunk: src row stride Ksrc, rows r0..r0+127, k-cols ch*64..+63
static __device__ __forceinline__ void stage_glds(const unsigned short* __restrict__ src,
                                                  int Ksrc, unsigned short* lds,
                                                  int wave, int lane){
  #pragma unroll
  for (int j = 0; j < 4; j++){
    int ublk = (j * 4 + wave) * 64;          // wave-uniform first 16B-unit
    int u    = ublk + lane;                  // this lane's unit
    int row  = u >> 3;                       // 8 units (128B) per row
    int unit = (u & 7) ^ (row & 7);          // source pre-swizzle
    __builtin_amdgcn_global_load_lds(
        (const __attribute__((address_space(1))) void*)(src + (size_t)row * Ksrc + unit * 8),
        (__attribute__((address_space(3))) void*)(lds + (size_t)ublk * 8),
        16, 0, 0);
  }
}

template<int K>
__global__ __launch_bounds__(256)
void gemm_glds(const unsigned short* __restrict__ A, const unsigned short* __restrict__ Wt,
               const float* __restrict__ bias, const float* __restrict__ res,
               void* __restrict__ C, int N, int flags){
  __shared__ unsigned short Als[2][128 * 64];
  __shared__ unsigned short Bls[2][128 * 64];
  int tid = threadIdx.x;
  int wave = tid >> 6, lane = tid & 63;
  int wm = wave >> 1, wn = wave & 1;
  int l16 = lane & 15, grp = lane >> 4;
  int r0 = blockIdx.y * 128, c0 = blockIdx.x * 128;

  const unsigned short* Ag = A  + (size_t)r0 * K;
  const unsigned short* Bg = Wt + (size_t)c0 * K;
  const int nch = K >> 6;

  // prologue: stage chunk 0 into buffer 0
  stage_glds(Ag, K, Als[0], wave, lane);
  stage_glds(Bg, K, Bls[0], wave, lane);

  f32x4 acc[4][4];
  #pragma unroll
  for (int m = 0; m < 4; m++)
    #pragma unroll
    for (int n = 0; n < 4; n++) acc[m][n] = (f32x4){0.f, 0.f, 0.f, 0.f};

  #pragma unroll
  for (int ch = 0; ch < nch; ch++){
    int b = ch & 1;
    __syncthreads();                          // drains prefetch (compiler: vmcnt(0))
    if (ch + 1 < nch){
      stage_glds(Ag + (ch + 1) * 64, K, Als[b ^ 1], wave, lane);
      stage_glds(Bg + (ch + 1) * 64, K, Bls[b ^ 1], wave, lane);
    }
    const unsigned short* Ab = Als[b];
    const unsigned short* Bb = Bls[b];
    #pragma unroll
    for (int kk = 0; kk < 2; kk++){
      short8 af[4], bfr[4];
      #pragma unroll
      for (int m = 0; m < 4; m++){
        int row = wm * 64 + m * 16 + l16;
        int unit = (kk * 4 + grp) ^ (row & 7);
        af[m] = *(const short8*)(Ab + row * 64 + unit * 8);
      }
      #pragma unroll
      for (int n = 0; n < 4; n++){
        int row = wn * 64 + n * 16 + l16;
        int unit = (kk * 4 + grp) ^ (row & 7);
        bfr[n] = *(const short8*)(Bb + row * 64 + unit * 8);
      }
      #pragma unroll
      for (int m = 0; m < 4; m++)
        #pragma unroll
        for (int n = 0; n < 4; n++)
          acc[m][n] = __builtin_amdgcn_mfma_f32_16x16x32_bf16(af[m], bfr[n], acc[m][n], 0, 0, 0);
    }
  }

  // epilogue: D col = l16, row = grp*4 + r (same mapping as verified r7 kernel)
  #pragma unroll
  for (int n = 0; n < 4; n++){
    int gc = c0 + wn * 64 + n * 16 + l16;
    float bv = (flags & 1) ? bias[gc] : 0.f;
    #pragma unroll
    for (int m = 0; m < 4; m++){
      int grb = r0 + wm * 64 + m * 16 + grp * 4;
      #pragma unroll
      for (int r = 0; r < 4; r++){
        float v = acc[m][n][r] + bv;
        if (flags & 2) v = gelu_f(v);
        if (flags & 4) v += res[(size_t)(grb + r) * N + gc];
        if (flags & 8) ((unsigned short*)C)[(size_t)(grb + r) * N + gc] = (unsigned short)bf16_rne(v);
        else           ((float*)C)[(size_t)(grb + r) * N + gc] = v;
      }
    }
  }
}

// ---------------- self-attention: bf16 MFMA flash (exact r4 code, 56us measured) ----
#define KSTR 40
#define VSTR 72
#define PSTR 72
__global__ __launch_bounds__(256)
void sa_attn_mfma(const unsigned short* __restrict__ qkv, unsigned short* __restrict__ ob){
  int m = blockIdx.z, h = blockIdx.y;
  int tid  = threadIdx.x;
  int wave = tid >> 6, lane = tid & 63;
  int qr = lane & 15, grp = lane >> 4;
  int q0 = blockIdx.x * 64 + wave * 16;

  __shared__ unsigned short Kls[2][64 * KSTR];
  __shared__ unsigned short Vls[2][32 * VSTR];
  __shared__ unsigned short Pls[4][16 * PSTR];
  unsigned short* Pw = Pls[wave];

  const float scale = 0.17677669529663687f;

  short8 qf = *(const short8*)(qkv + ((size_t)(m * NCTX + q0 + qr)) * 768 + h * 32 + grp * 8);

  int skey = tid >> 2;
  int scol = (tid & 3) * 8;
  const unsigned short* kbase = qkv + (size_t)m * NCTX * 768 + 256 + h * 32 + scol;

  uint4 kreg = *(const uint4*)(kbase + (size_t)skey * 768);
  uint4 vreg = *(const uint4*)(kbase + (size_t)skey * 768 + 256);

  float mq = -1e30f, lq = 0.0f;
  f32x4 acc0 = {0.f, 0.f, 0.f, 0.f};
  f32x4 acc1 = {0.f, 0.f, 0.f, 0.f};

  {
    *(uint4*)&Kls[0][skey * KSTR + scol] = kreg;
    unsigned int vv[4] = {vreg.x, vreg.y, vreg.z, vreg.w};
    #pragma unroll
    for (int j = 0; j < 4; j++){
      Vls[0][(scol + 2 * j    ) * VSTR + skey] = (unsigned short)(vv[j] & 0xffffu);
      Vls[0][(scol + 2 * j + 1) * VSTR + skey] = (unsigned short)(vv[j] >> 16);
    }
  }

  for (int kt = 0; kt < NCTX / 64; kt++){
    int b = kt & 1;
    __syncthreads();
    if (kt + 1 < NCTX / 64){
      kreg = *(const uint4*)(kbase + (size_t)((kt + 1) * 64 + skey) * 768);
      vreg = *(const uint4*)(kbase + (size_t)((kt + 1) * 64 + skey) * 768 + 256);
    }

    f32x4 s0 = {0.f,0.f,0.f,0.f}, s1 = {0.f,0.f,0.f,0.f};
    f32x4 s2 = {0.f,0.f,0.f,0.f}, s3 = {0.f,0.f,0.f,0.f};
    {
      const short8 k0 = *(const short8*)&Kls[b][( 0 + qr) * KSTR + grp * 8];
      const short8 k1 = *(const short8*)&Kls[b][(16 + qr) * KSTR + grp * 8];
      const short8 k2 = *(const short8*)&Kls[b][(32 + qr) * KSTR + grp * 8];
      const short8 k3 = *(const short8*)&Kls[b][(48 + qr) * KSTR + grp * 8];
      s0 = __builtin_amdgcn_mfma_f32_16x16x32_bf16(k0, qf, s0, 0, 0, 0);
      s1 = __builtin_amdgcn_mfma_f32_16x16x32_bf16(k1, qf, s1, 0, 0, 0);
      s2 = __builtin_amdgcn_mfma_f32_16x16x32_bf16(k2, qf, s2, 0, 0, 0);
      s3 = __builtin_amdgcn_mfma_f32_16x16x32_bf16(k3, qf, s3, 0, 0, 0);
    }

    float sc[4][4];
    #pragma unroll
    for (int r = 0; r < 4; r++){
      sc[0][r] = s0[r] * scale; sc[1][r] = s1[r] * scale;
      sc[2][r] = s2[r] * scale; sc[3][r] = s3[r] * scale;
    }
    float tm = sc[0][0];
    #pragma unroll
    for (int kb = 0; kb < 4; kb++)
      #pragma unroll
      for (int r = 0; r < 4; r++) tm = fmaxf(tm, sc[kb][r]);
    tm = fmaxf(tm, __shfl_xor(tm, 16));
    tm = fmaxf(tm, __shfl_xor(tm, 32));
    float mn = fmaxf(mq, tm);
    float corr = __expf(mq - mn);
    float ts = 0.f;
    float p[4][4];
    #pragma unroll
    for (int kb = 0; kb < 4; kb++)
      #pragma unroll
      for (int r = 0; r < 4; r++){
        float pv = __expf(sc[kb][r] - mn);
        p[kb][r] = pv; ts += pv;
      }
    ts += __shfl_xor(ts, 16);
    ts += __shfl_xor(ts, 32);
    lq = lq * corr + ts;
    mq = mn;
    #pragma unroll
    for (int r = 0; r < 4; r++){ acc0[r] *= corr; acc1[r] *= corr; }

    #pragma unroll
    for (int kb = 0; kb < 4; kb++){
      *(unsigned int*)&Pw[qr * PSTR + kb * 16 + grp * 4]     = pack_bf16x2(p[kb][0], p[kb][1]);
      *(unsigned int*)&Pw[qr * PSTR + kb * 16 + grp * 4 + 2] = pack_bf16x2(p[kb][2], p[kb][3]);
    }

    #pragma unroll
    for (int hh = 0; hh < 2; hh++){
      const short8 pf = *(const short8*)&Pw[qr * PSTR + hh * 32 + grp * 8];
      const short8 v0 = *(const short8*)&Vls[b][( 0 + qr) * VSTR + hh * 32 + grp * 8];
      const short8 v1 = *(const short8*)&Vls[b][(16 + qr) * VSTR + hh * 32 + grp * 8];
      acc0 = __builtin_amdgcn_mfma_f32_16x16x32_bf16(v0, pf, acc0, 0, 0, 0);
      acc1 = __builtin_amdgcn_mfma_f32_16x16x32_bf16(v1, pf, acc1, 0, 0, 0);
    }

    if (kt + 1 < NCTX / 64){
      *(uint4*)&Kls[b ^ 1][skey * KSTR + scol] = kreg;
      unsigned int vv[4] = {vreg.x, vreg.y, vreg.z, vreg.w};
      #pragma unroll
      for (int j = 0; j < 4; j++){
        Vls[b ^ 1][(scol + 2 * j    ) * VSTR + skey] = (unsigned short)(vv[j] & 0xffffu);
        Vls[b ^ 1][(scol + 2 * j + 1) * VSTR + skey] = (unsigned short)(vv[j] >> 16);
      }
    }
  }

  float inv = 1.0f / lq;
  unsigned short* op = ob + ((size_t)(m * NCTX + q0 + qr)) * DMODEL + h * DHEAD;
  uint2 o16a, o16b;
  o16a.x = pack_bf16x2(acc0[0] * inv, acc0[1] * inv);
  o16a.y = pack_bf16x2(acc0[2] * inv, acc0[3] * inv);
  o16b.x = pack_bf16x2(acc1[0] * inv, acc1[1] * inv);
  o16b.y = pack_bf16x2(acc1[2] * inv, acc1[3] * inv);
  *(uint2*)(op + grp * 4)      = o16a;
  *(uint2*)(op + 16 + grp * 4) = o16b;
}

// ---------------- cross-attention over 9 gathered neighbours (bf16 out) -----------
__global__ __launch_bounds__(256)
void ca_attn_kernel(const float* __restrict__ qb, const float* __restrict__ kv,
                    const int* __restrict__ idx, const float* __restrict__ mask,
                    unsigned short* __restrict__ ob){
  int g = blockIdx.x;
  int m = g >> 11;
  int tid = threadIdx.x;
  const float scale = 0.17677669529663687f;
  float q = qb[(size_t)g * DMODEL + tid] * scale;
  float s[KNB];
  int rws[KNB];
  #pragma unroll
  for (int k = 0; k < KNB; k++){
    int row = idx[(size_t)g * KNB + k];
    rws[k] = row;
    float p = q * kv[((size_t)(m * NCTX + row)) * 512 + tid];
    #pragma unroll
    for (int off = 16; off > 0; off >>= 1) p += __shfl_xor(p, off, 32);
    s[k] = (mask[(size_t)g * KNB + k] > 0.5f) ? p : -1e30f;
  }
  float sm = s[0];
  #pragma unroll
  for (int k = 1; k < KNB; k++) sm = fmaxf(sm, s[k]);
  float den = 0.f, w[KNB];
  #pragma unroll
  for (int k = 0; k < KNB; k++){ w[k] = __expf(s[k] - sm); den += w[k]; }
  float inv = 1.0f / den;
  float o = 0.f;
  #pragma unroll
  for (int k = 0; k < KNB; k++)
    o += w[k] * kv[((size_t)(m * NCTX + rws[k])) * 512 + 256 + tid];
  ob[(size_t)g * DMODEL + tid] = (unsigned short)bf16_rne(o * inv);
}

// ---------------- host launch helper ----------------
static inline void launch_gemm(const unsigned short* A, const unsigned short* Wt,
                               const float* bias, const float* res, void* C,
                               int R, int K, int N, int flags, hipStream_t stream){
  dim3 grid(N / 128, R / 128);
  if (K == 256)
    gemm_glds<256><<<grid, 256, 0, stream>>>(A, Wt, bias, res, C, N, flags);
  else
    gemm_glds<512><<<grid, 256, 0, stream>>>(A, Wt, bias, res, C, N, flags);
}

// ---------------- host launcher ----------------
extern "C" void kernel_launch(void* const* d_in, const int* in_sizes, int n_in,
                              void* d_out, int out_size, void* d_ws, size_t ws_size,
                              hipStream_t stream){
  const float* xc      = (const float*)d_in[0];
  const float* zc_in   = (const float*)d_in[1];
  const float* xt      = (const float*)d_in[2];
  const float* zt_in   = (const float*)d_in[3];
  const float* sa_wqkv = (const float*)d_in[4];
  const float* sa_wo   = (const float*)d_in[5];
  const float* sa_ln1  = (const float*)d_in[6];
  const float* sa_ln2  = (const float*)d_in[7];
  const float* sa_w1   = (const float*)d_in[8];
  const float* sa_b1   = (const float*)d_in[9];
  const float* sa_w2   = (const float*)d_in[10];
  const float* sa_b2   = (const float*)d_in[11];
  const float* ca_wq   = (const float*)d_in[12];
  const float* ca_wkv  = (const float*)d_in[13];
  const float* ca_wo   = (const float*)d_in[14];
  const float* ca_lnq  = (const float*)d_in[15];
  const float* ca_lnkv = (const float*)d_in[16];
  const float* ca_ln2  = (const float*)d_in[17];
  const float* ca_w1   = (const float*)d_in[18];
  const float* ca_b1   = (const float*)d_in[19];
  const float* ca_w2   = (const float*)d_in[20];
  const float* ca_b2   = (const float*)d_in[21];

  if (ws_size < (size_t)WS_FLOATS * sizeof(float)) return;
  float* ws    = (float*)d_ws;
  float* zc    = ws + ZC_OFF;
  unsigned short* hb16 = (unsigned short*)(ws + H_OFF);
  float* qkvb  = ws + QKV_OFF;   // aliased: bf16 qkv / fp32 CA kv / bf16 ffn-mid
  unsigned short* qkv16 = (unsigned short*)qkvb;
  unsigned short* wt    = (unsigned short*)(ws + WT_OFF);
  float* fb    = ws + FB_OFF;
  float* qb    = ws + Q_OFF;
  unsigned short* ob16 = (unsigned short*)(ws + O_OFF);
  int*   idxb  = (int*)(ws + IDX_OFF);
  float* maskb = ws + MASK_OFF;
  float* zt    = (float*)d_out;

  // ---- weight prep (transpose + gamma row-scale) ----
  TTable tt;
  for (int l = 0; l < LAYERS; l++){
    int b = l * WT_LAYER, i = l * 9;
    tt.e[i + 0] = { sa_wqkv + (size_t)l * 256 * 768, sa_ln1  + l * 512, b + WT_QKV,  256, 768 };
    tt.e[i + 1] = { sa_wo   + (size_t)l * 256 * 256, nullptr,           b + WT_WO,   256, 256 };
    tt.e[i + 2] = { sa_w1   + (size_t)l * 256 * 512, sa_ln2  + l * 512, b + WT_W1,   256, 512 };
    tt.e[i + 3] = { sa_w2   + (size_t)l * 512 * 256, nullptr,           b + WT_W2,   512, 256 };
    tt.e[i + 4] = { ca_wq   + (size_t)l * 256 * 256, ca_lnq  + l * 512, b + WT_CWQ,  256, 256 };
    tt.e[i + 5] = { ca_wkv  + (size_t)l * 256 * 512, ca_lnkv + l * 512, b + WT_CWKV, 256, 512 };
    tt.e[i + 6] = { ca_wo   + (size_t)l * 256 * 256, nullptr,           b + WT_CWO,  256, 256 };
    tt.e[i + 7] = { ca_w1   + (size_t)l * 256 * 512, ca_ln2  + l * 512, b + WT_CW1,  256, 512 };
    tt.e[i + 8] = { ca_w2   + (size_t)l * 512 * 256, nullptr,           b + WT_CW2,  512, 256 };
  }
  wprep_kernel<<<dim3(24, 16, 18), dim3(32, 8), 0, stream>>>(tt, wt);

  // ---- beta fold into biases (parallel) ----
  BTable bt;
  for (int l = 0; l < LAYERS; l++){
    int fo = l * FB_LAYER, i = l * 5;
    bt.e[i + 0] = { sa_wqkv + (size_t)l * 256 * 768, sa_ln1  + l * 512 + 256, nullptr,        fo + FB_QKV, 768 };
    bt.e[i + 1] = { sa_w1   + (size_t)l * 256 * 512, sa_ln2  + l * 512 + 256, sa_b1 + l * FF, fo + FB_W1,  512 };
    bt.e[i + 2] = { ca_wkv  + (size_t)l * 256 * 512, ca_lnkv + l * 512 + 256, nullptr,        fo + FB_WKV, 512 };
    bt.e[i + 3] = { ca_wq   + (size_t)l * 256 * 256, ca_lnq  + l * 512 + 256, nullptr,        fo + FB_WQ,  256 };
    bt.e[i + 4] = { ca_w1   + (size_t)l * 256 * 512, ca_ln2  + l * 512 + 256, ca_b1 + l * FF, fo + FB_CW1, 512 };
  }
  bfold_kernel<<<dim3(10, 12), 256, 0, stream>>>(bt, fb);

  nn_idx_kernel<<<(MB * NTGT) / 256, 256, 0, stream>>>(xc, xt, idxb, maskb);

  for (int l = 0; l < LAYERS; l++){
    const unsigned short* wl = wt + (size_t)l * WT_LAYER;
    const float* fl = fb + (size_t)l * FB_LAYER;
    const float* zc_src = (l == 0) ? zc_in : zc;
    const float* zt_src = (l == 0) ? zt_in : zt;

    // ---------- self-attention block on zc ----------
    ln_norm<<<RC / 4, 256, 0, stream>>>(zc_src, hb16, RC);
    launch_gemm(hb16, wl + WT_QKV, fl + FB_QKV, nullptr, qkv16, RC, 256, 768, 1 | 8, stream);
    sa_attn_mfma<<<dim3(NCTX / 64, NHEAD, MB), 256, 0, stream>>>(qkv16, ob16);
    launch_gemm(ob16, wl + WT_WO, nullptr, zc_src, zc, RC, 256, 256, 4, stream);
    ln_norm<<<RC / 4, 256, 0, stream>>>(zc, hb16, RC);
    launch_gemm(hb16, wl + WT_W1, fl + FB_W1, nullptr, qkv16, RC, 256, 512, 1 | 2 | 8, stream);
    launch_gemm(qkv16, wl + WT_W2, sa_b2 + l * DMODEL, zc, zc, RC, 512, 256, 1 | 4, stream);

    // ---------- cross-attention block on zt ----------
    ln_norm<<<RC / 4, 256, 0, stream>>>(zc, hb16, RC);
    launch_gemm(hb16, wl + WT_CWKV, fl + FB_WKV, nullptr, qkvb, RC, 256, 512, 1, stream);
    ln_norm<<<RT / 4, 256, 0, stream>>>(zt_src, hb16, RT);
    launch_gemm(hb16, wl + WT_CWQ, fl + FB_WQ, nullptr, qb, RT, 256, 256, 1, stream);
    ca_attn_kernel<<<RT, 256, 0, stream>>>(qb, qkvb, idxb, maskb, ob16);
    launch_gemm(ob16, wl + WT_CWO, nullptr, zt_src, zt, RT, 256, 256, 4, stream);
    ln_norm<<<RT / 4, 256, 0, stream>>>(zt, hb16, RT);
    launch_gemm(hb16, wl + WT_CW1, fl + FB_CW1, nullptr, qkv16, RT, 256, 512, 1 | 2 | 8, stream);
    launch_gemm(qkv16, wl + WT_CW2, ca_b2 + l * DMODEL, zt, zt, RT, 512, 256, 1 | 4, stream);
  }
}

// Round 10
// 400.001 us; speedup vs baseline: 1.6466x; 1.3662x over previous
//
#include <hip/hip_runtime.h>
#include <math.h>

// ---------------- problem constants ----------------
#define LAYERS 2
#define DMODEL 256
#define NHEAD  8
#define DHEAD  32
#define FF     512
#define KNB    9
#define MB     4
#define G1D    40
#define G2D    40
#define NTGT   2048
#define NCTX   1600          // G1D*G2D
#define RC     (MB*NCTX)     // 6400 grid rows
#define RT     (MB*NTGT)     // 8192 target rows

typedef __attribute__((ext_vector_type(8))) short short8;   // 8 bf16 (4 VGPRs)
typedef __attribute__((ext_vector_type(4))) float f32x4;    // mfma C/D

#if __has_builtin(__builtin_amdgcn_exp2f)
#define EXP2(x) __builtin_amdgcn_exp2f(x)
#else
#define EXP2(x) exp2f(x)
#endif
#define L2E 1.4426950408889634f

// ---------------- workspace layout (float offsets) ----------------
#define ZC_OFF    0
#define H_OFF     1638400                      // bf16 LN output
#define QKV_OFF   (H_OFF + 2097152)
#define WT_OFF    (QKV_OFF + 3400000)          // bf16 wT (tail of QKV region)
#define FB_OFF    (QKV_OFF + 4500000)          // folded biases
#define Q_OFF     (QKV_OFF + 4915200)
#define O_OFF     (Q_OFF + 2097152)
#define IDX_OFF   (O_OFF + 2097152)
#define MASK_OFF  (IDX_OFF + 73728)
#define WS_FLOATS (MASK_OFF + 73728)

// per-layer wT offsets (shorts)
#define WT_LAYER   1048576
#define WT_QKV     0
#define WT_WO      196608
#define WT_W1      262144
#define WT_W2      393216
#define WT_CWQ     524288
#define WT_CWKV    589824
#define WT_CWO     720896
#define WT_CW1     786432
#define WT_CW2     917504
// per-layer folded-bias offsets (floats), layer stride 2560
#define FB_LAYER   2560
#define FB_QKV     0
#define FB_W1      768
#define FB_WKV     1280
#define FB_WQ      1792
#define FB_CW1     2048

static __device__ __forceinline__ float gelu_f(float x){
  float t = tanhf(0.7978845608028654f * (x + 0.044715f * x * x * x));
  return 0.5f * x * (1.0f + t);
}
static __device__ __forceinline__ unsigned int bf16_rne(float x){
  unsigned int u = __float_as_uint(x);
  return (u + 0x7fffu + ((u >> 16) & 1u)) >> 16;
}
static __device__ __forceinline__ unsigned int pack_bf16x2(float lo, float hi){
  return bf16_rne(lo) | (bf16_rne(hi) << 16);
}

// ---------------- weight prep: fp32 [K][N] -> bf16 [N][K], row-scaled by gamma -------
struct TDesc { const float* src; const float* gamma; int dstoff; int K; int N; };
struct TTable { TDesc e[18]; };

__global__ __launch_bounds__(256)
void wprep_kernel(TTable t, unsigned short* __restrict__ wt){
  TDesc d = t.e[blockIdx.z];
  int n0 = blockIdx.x * 32, k0 = blockIdx.y * 32;
  if (n0 >= d.N || k0 >= d.K) return;
  __shared__ float tile[32][33];
  int tx = threadIdx.x, ty = threadIdx.y;
  #pragma unroll
  for (int j = 0; j < 4; j++){
    int k = k0 + ty * 4 + j;
    float v = d.src[(size_t)k * d.N + n0 + tx];
    if (d.gamma) v *= d.gamma[k];
    tile[ty * 4 + j][tx] = v;
  }
  __syncthreads();
  #pragma unroll
  for (int j = 0; j < 4; j++)
    wt[(size_t)d.dstoff + (size_t)(n0 + ty * 4 + j) * d.K + k0 + tx] =
        (unsigned short)bf16_rne(tile[tx][ty * 4 + j]);
}

// ---------------- bias fold (parallel): fb[n] = base[n] + sum_k beta[k]*W[k][n] ------
struct BDesc { const float* W; const float* beta; const float* base; int outoff; int N; };
struct BTable { BDesc e[10]; };

__global__ __launch_bounds__(256)
void bfold_kernel(BTable t, float* __restrict__ fb){
  BDesc d = t.e[blockIdx.x];
  int n = blockIdx.y * 64 + (threadIdx.x >> 2);
  int q = threadIdx.x & 3;
  if (n >= d.N) return;
  float s = 0.f;
  #pragma unroll 4
  for (int k = q * 64; k < q * 64 + 64; k++)
    s += d.beta[k] * d.W[(size_t)k * d.N + n];
  s += __shfl_xor(s, 1);
  s += __shfl_xor(s, 2);
  if (q == 0) fb[d.outoff + n] = s + (d.base ? d.base[n] : 0.f);
}

// ---------------- nearest-grid-neighbour index/mask precompute ----------------
__global__ void nn_idx_kernel(const float* __restrict__ xc, const float* __restrict__ xt,
                              int* __restrict__ idx, float* __restrict__ mask){
  int g = blockIdx.x * blockDim.x + threadIdx.x;
  if (g >= MB * NTGT) return;
  int m = g >> 11;
  float x0 = xt[(size_t)g * 2 + 0];
  float x1 = xt[(size_t)g * 2 + 1];
  const float* xcm = xc + (size_t)m * G1D * G2D * 2;
  int n0 = 0; float b0 = 1e30f;
  for (int i = 0; i < G1D; i++){
    float d = fabsf(x0 - xcm[i * (G2D * 2)]);
    if (d < b0){ b0 = d; n0 = i; }
  }
  int n1 = 0; float b1 = 1e30f;
  for (int j = 0; j < G2D; j++){
    float d = fabsf(x1 - xcm[j * 2 + 1]);
    if (d < b1){ b1 = d; n1 = j; }
  }
  #pragma unroll
  for (int a = 0; a < 3; a++){
    int r0 = n0 + a - 1;
    bool v0 = (r0 >= 0) && (r0 < G1D);
    int i0 = min(max(r0, 0), G1D - 1);
    #pragma unroll
    for (int b = 0; b < 3; b++){
      int r1 = n1 + b - 1;
      bool v1 = (r1 >= 0) && (r1 < G2D);
      int i1 = min(max(r1, 0), G2D - 1);
      idx [(size_t)g * KNB + a * 3 + b] = i0 * G2D + i1;
      mask[(size_t)g * KNB + a * 3 + b] = (v0 && v1) ? 1.0f : 0.0f;
    }
  }
}

// ---------------- LayerNorm normalize-only (affine folded into wT/bias), bf16 out ----
__global__ __launch_bounds__(256)
void ln_norm(const float* __restrict__ x, unsigned short* __restrict__ y, int rows){
  int gw   = blockIdx.x * 4 + (threadIdx.x >> 6);
  int lane = threadIdx.x & 63;
  if (gw >= rows) return;
  const float* xr = x + (size_t)gw * DMODEL;
  int d0 = lane * 4;
  float4 xv = *(const float4*)(xr + d0);
  float s = xv.x + xv.y + xv.z + xv.w;
  #pragma unroll
  for (int off = 32; off > 0; off >>= 1) s += __shfl_xor(s, off);
  float mu = s * (1.0f / DMODEL);
  float dx0 = xv.x - mu, dx1 = xv.y - mu, dx2 = xv.z - mu, dx3 = xv.w - mu;
  float v = dx0*dx0 + dx1*dx1 + dx2*dx2 + dx3*dx3;
  #pragma unroll
  for (int off = 32; off > 0; off >>= 1) v += __shfl_xor(v, off);
  float rs = rsqrtf(v * (1.0f / DMODEL) + 1e-5f);
  uint2 w;
  w.x = pack_bf16x2(dx0 * rs, dx1 * rs);
  w.y = pack_bf16x2(dx2 * rs, dx3 * rs);
  *(uint2*)(y + (size_t)gw * DMODEL + d0) = w;
}

// ================= MFMA GEMM, templated tile (MTxNT), BK=64 dbuf, glds staging ======
// A bf16 [R][K], Wt bf16 [N][K]. Linear LDS dest + inverse-swizzled global source +
// swizzled ds_read (rule #21; verified r9). Tiles: 64x64 (N<=512) / 64x128 (N=768).
// flags: 1=bias, 2=gelu, 4=residual(fp32), 8=bf16 out

template<int ROWS>
static __device__ __forceinline__ void stage_glds(const unsigned short* __restrict__ src,
                                                  int Ksrc, unsigned short* lds,
                                                  int wave, int lane){
  #pragma unroll
  for (int j = 0; j < ROWS / 32; j++){
    int ublk = (j * 4 + wave) * 64;          // wave-uniform first 16B-unit
    int u    = ublk + lane;
    int row  = u >> 3;                       // 8 units (128B) per row
    int unit = (u & 7) ^ (row & 7);          // source pre-swizzle
    __builtin_amdgcn_global_load_lds(
        (const __attribute__((address_space(1))) void*)(src + (size_t)row * Ksrc + unit * 8),
        (__attribute__((address_space(3))) void*)(lds + (size_t)ublk * 8),
        16, 0, 0);
  }
}

template<int K, int MT, int NT>
__global__ __launch_bounds__(256)
void gemm_glds(const unsigned short* __restrict__ A, const unsigned short* __restrict__ Wt,
               const float* __restrict__ bias, const float* __restrict__ res,
               void* __restrict__ C, int N, int flags){
  const int MFR = MT / 32, NFR = NT / 32;    // 16x16 frags per wave
  __shared__ unsigned short Als[2][MT * 64];
  __shared__ unsigned short Bls[2][NT * 64];
  int tid = threadIdx.x;
  int wave = tid >> 6, lane = tid & 63;
  int wm = wave >> 1, wn = wave & 1;
  int l16 = lane & 15, grp = lane >> 4;
  int r0 = blockIdx.y * MT, c0 = blockIdx.x * NT;

  const unsigned short* Ag = A  + (size_t)r0 * K;
  const unsigned short* Bg = Wt + (size_t)c0 * K;
  const int nch = K >> 6;

  stage_glds<MT>(Ag, K, Als[0], wave, lane);
  stage_glds<NT>(Bg, K, Bls[0], wave, lane);

  f32x4 acc[MFR][NFR];
  #pragma unroll
  for (int m = 0; m < MFR; m++)
    #pragma unroll
    for (int n = 0; n < NFR; n++) acc[m][n] = (f32x4){0.f, 0.f, 0.f, 0.f};

  #pragma unroll
  for (int ch = 0; ch < nch; ch++){
    int b = ch & 1;
    __syncthreads();
    if (ch + 1 < nch){
      stage_glds<MT>(Ag + (ch + 1) * 64, K, Als[b ^ 1], wave, lane);
      stage_glds<NT>(Bg + (ch + 1) * 64, K, Bls[b ^ 1], wave, lane);
    }
    const unsigned short* Ab = Als[b];
    const unsigned short* Bb = Bls[b];
    #pragma unroll
    for (int kk = 0; kk < 2; kk++){
      short8 af[MFR], bfr[NFR];
      #pragma unroll
      for (int m = 0; m < MFR; m++){
        int row = wm * (MT / 2) + m * 16 + l16;
        int unit = (kk * 4 + grp) ^ (row & 7);
        af[m] = *(const short8*)(Ab + row * 64 + unit * 8);
      }
      #pragma unroll
      for (int n = 0; n < NFR; n++){
        int row = wn * (NT / 2) + n * 16 + l16;
        int unit = (kk * 4 + grp) ^ (row & 7);
        bfr[n] = *(const short8*)(Bb + row * 64 + unit * 8);
      }
      #pragma unroll
      for (int m = 0; m < MFR; m++)
        #pragma unroll
        for (int n = 0; n < NFR; n++)
          acc[m][n] = __builtin_amdgcn_mfma_f32_16x16x32_bf16(af[m], bfr[n], acc[m][n], 0, 0, 0);
    }
  }

  #pragma unroll
  for (int n = 0; n < NFR; n++){
    int gc = c0 + wn * (NT / 2) + n * 16 + l16;
    float bv = (flags & 1) ? bias[gc] : 0.f;
    #pragma unroll
    for (int m = 0; m < MFR; m++){
      int grb = r0 + wm * (MT / 2) + m * 16 + grp * 4;
      #pragma unroll
      for (int r = 0; r < 4; r++){
        float v = acc[m][n][r] + bv;
        if (flags & 2) v = gelu_f(v);
        if (flags & 4) v += res[(size_t)(grb + r) * N + gc];
        if (flags & 8) ((unsigned short*)C)[(size_t)(grb + r) * N + gc] = (unsigned short)bf16_rne(v);
        else           ((float*)C)[(size_t)(grb + r) * N + gc] = v;
      }
    }
  }
}

// ---------------- self-attention: bf16 MFMA flash (r4 structure; exp -> native exp2) -
#define KSTR 40
#define VSTR 72
#define PSTR 72
__global__ __launch_bounds__(256)
void sa_attn_mfma(const unsigned short* __restrict__ qkv, unsigned short* __restrict__ ob){
  int m = blockIdx.z, h = blockIdx.y;
  int tid  = threadIdx.x;
  int wave = tid >> 6, lane = tid & 63;
  int qr = lane & 15, grp = lane >> 4;
  int q0 = blockIdx.x * 64 + wave * 16;

  __shared__ unsigned short Kls[2][64 * KSTR];
  __shared__ unsigned short Vls[2][32 * VSTR];
  __shared__ unsigned short Pls[4][16 * PSTR];
  unsigned short* Pw = Pls[wave];

  const float scale = 0.17677669529663687f;

  short8 qf = *(const short8*)(qkv + ((size_t)(m * NCTX + q0 + qr)) * 768 + h * 32 + grp * 8);

  int skey = tid >> 2;
  int scol = (tid & 3) * 8;
  const unsigned short* kbase = qkv + (size_t)m * NCTX * 768 + 256 + h * 32 + scol;

  uint4 kreg = *(const uint4*)(kbase + (size_t)skey * 768);
  uint4 vreg = *(const uint4*)(kbase + (size_t)skey * 768 + 256);

  float mq = -1e30f, lq = 0.0f;
  f32x4 acc0 = {0.f, 0.f, 0.f, 0.f};
  f32x4 acc1 = {0.f, 0.f, 0.f, 0.f};

  {
    *(uint4*)&Kls[0][skey * KSTR + scol] = kreg;
    unsigned int vv[4] = {vreg.x, vreg.y, vreg.z, vreg.w};
    #pragma unroll
    for (int j = 0; j < 4; j++){
      Vls[0][(scol + 2 * j    ) * VSTR + skey] = (unsigned short)(vv[j] & 0xffffu);
      Vls[0][(scol + 2 * j + 1) * VSTR + skey] = (unsigned short)(vv[j] >> 16);
    }
  }

  for (int kt = 0; kt < NCTX / 64; kt++){
    int b = kt & 1;
    __syncthreads();
    if (kt + 1 < NCTX / 64){
      kreg = *(const uint4*)(kbase + (size_t)((kt + 1) * 64 + skey) * 768);
      vreg = *(const uint4*)(kbase + (size_t)((kt + 1) * 64 + skey) * 768 + 256);
    }

    f32x4 s0 = {0.f,0.f,0.f,0.f}, s1 = {0.f,0.f,0.f,0.f};
    f32x4 s2 = {0.f,0.f,0.f,0.f}, s3 = {0.f,0.f,0.f,0.f};
    {
      const short8 k0 = *(const short8*)&Kls[b][( 0 + qr) * KSTR + grp * 8];
      const short8 k1 = *(const short8*)&Kls[b][(16 + qr) * KSTR + grp * 8];
      const short8 k2 = *(const short8*)&Kls[b][(32 + qr) * KSTR + grp * 8];
      const short8 k3 = *(const short8*)&Kls[b][(48 + qr) * KSTR + grp * 8];
      s0 = __builtin_amdgcn_mfma_f32_16x16x32_bf16(k0, qf, s0, 0, 0, 0);
      s1 = __builtin_amdgcn_mfma_f32_16x16x32_bf16(k1, qf, s1, 0, 0, 0);
      s2 = __builtin_amdgcn_mfma_f32_16x16x32_bf16(k2, qf, s2, 0, 0, 0);
      s3 = __builtin_amdgcn_mfma_f32_16x16x32_bf16(k3, qf, s3, 0, 0, 0);
    }

    float sc[4][4];
    #pragma unroll
    for (int r = 0; r < 4; r++){
      sc[0][r] = s0[r] * scale; sc[1][r] = s1[r] * scale;
      sc[2][r] = s2[r] * scale; sc[3][r] = s3[r] * scale;
    }
    float tm = sc[0][0];
    #pragma unroll
    for (int kb = 0; kb < 4; kb++)
      #pragma unroll
      for (int r = 0; r < 4; r++) tm = fmaxf(tm, sc[kb][r]);
    tm = fmaxf(tm, __shfl_xor(tm, 16));
    tm = fmaxf(tm, __shfl_xor(tm, 32));
    float mn = fmaxf(mq, tm);
    float corr = EXP2((mq - mn) * L2E);
    float ts = 0.f;
    float p[4][4];
    #pragma unroll
    for (int kb = 0; kb < 4; kb++)
      #pragma unroll
      for (int r = 0; r < 4; r++){
        float pv = EXP2((sc[kb][r] - mn) * L2E);
        p[kb][r] = pv; ts += pv;
      }
    ts += __shfl_xor(ts, 16);
    ts += __shfl_xor(ts, 32);
    lq = lq * corr + ts;
    mq = mn;
    #pragma unroll
    for (int r = 0; r < 4; r++){ acc0[r] *= corr; acc1[r] *= corr; }

    #pragma unroll
    for (int kb = 0; kb < 4; kb++){
      *(unsigned int*)&Pw[qr * PSTR + kb * 16 + grp * 4]     = pack_bf16x2(p[kb][0], p[kb][1]);
      *(unsigned int*)&Pw[qr * PSTR + kb * 16 + grp * 4 + 2] = pack_bf16x2(p[kb][2], p[kb][3]);
    }

    #pragma unroll
    for (int hh = 0; hh < 2; hh++){
      const short8 pf = *(const short8*)&Pw[qr * PSTR + hh * 32 + grp * 8];
      const short8 v0 = *(const short8*)&Vls[b][( 0 + qr) * VSTR + hh * 32 + grp * 8];
      const short8 v1 = *(const short8*)&Vls[b][(16 + qr) * VSTR + hh * 32 + grp * 8];
      acc0 = __builtin_amdgcn_mfma_f32_16x16x32_bf16(v0, pf, acc0, 0, 0, 0);
      acc1 = __builtin_amdgcn_mfma_f32_16x16x32_bf16(v1, pf, acc1, 0, 0, 0);
    }

    if (kt + 1 < NCTX / 64){
      *(uint4*)&Kls[b ^ 1][skey * KSTR + scol] = kreg;
      unsigned int vv[4] = {vreg.x, vreg.y, vreg.z, vreg.w};
      #pragma unroll
      for (int j = 0; j < 4; j++){
        Vls[b ^ 1][(scol + 2 * j    ) * VSTR + skey] = (unsigned short)(vv[j] & 0xffffu);
        Vls[b ^ 1][(scol + 2 * j + 1) * VSTR + skey] = (unsigned short)(vv[j] >> 16);
      }
    }
  }

  float inv = 1.0f / lq;
  unsigned short* op = ob + ((size_t)(m * NCTX + q0 + qr)) * DMODEL + h * DHEAD;
  uint2 o16a, o16b;
  o16a.x = pack_bf16x2(acc0[0] * inv, acc0[1] * inv);
  o16a.y = pack_bf16x2(acc0[2] * inv, acc0[3] * inv);
  o16b.x = pack_bf16x2(acc1[0] * inv, acc1[1] * inv);
  o16b.y = pack_bf16x2(acc1[2] * inv, acc1[3] * inv);
  *(uint2*)(op + grp * 4)      = o16a;
  *(uint2*)(op + 16 + grp * 4) = o16b;
}

// ---------------- cross-attention over 9 gathered neighbours (bf16 out) -----------
__global__ __launch_bounds__(256)
void ca_attn_kernel(const float* __restrict__ qb, const float* __restrict__ kv,
                    const int* __restrict__ idx, const float* __restrict__ mask,
                    unsigned short* __restrict__ ob){
  int g = blockIdx.x;
  int m = g >> 11;
  int tid = threadIdx.x;
  const float scale = 0.17677669529663687f;
  float q = qb[(size_t)g * DMODEL + tid] * scale;
  float s[KNB];
  int rws[KNB];
  #pragma unroll
  for (int k = 0; k < KNB; k++){
    int row = idx[(size_t)g * KNB + k];
    rws[k] = row;
    float p = q * kv[((size_t)(m * NCTX + row)) * 512 + tid];
    #pragma unroll
    for (int off = 16; off > 0; off >>= 1) p += __shfl_xor(p, off, 32);
    s[k] = (mask[(size_t)g * KNB + k] > 0.5f) ? p : -1e30f;
  }
  float sm = s[0];
  #pragma unroll
  for (int k = 1; k < KNB; k++) sm = fmaxf(sm, s[k]);
  float den = 0.f, w[KNB];
  #pragma unroll
  for (int k = 0; k < KNB; k++){ w[k] = __expf(s[k] - sm); den += w[k]; }
  float inv = 1.0f / den;
  float o = 0.f;
  #pragma unroll
  for (int k = 0; k < KNB; k++)
    o += w[k] * kv[((size_t)(m * NCTX + rws[k])) * 512 + 256 + tid];
  ob[(size_t)g * DMODEL + tid] = (unsigned short)bf16_rne(o * inv);
}

// ---------------- host launch helper ----------------
static inline void launch_gemm(const unsigned short* A, const unsigned short* Wt,
                               const float* bias, const float* res, void* C,
                               int R, int K, int N, int flags, hipStream_t stream){
  if (N == 768){
    gemm_glds<256, 64, 128><<<dim3(N / 128, R / 64), 256, 0, stream>>>(A, Wt, bias, res, C, N, flags);
  } else if (K == 256){
    gemm_glds<256, 64, 64><<<dim3(N / 64, R / 64), 256, 0, stream>>>(A, Wt, bias, res, C, N, flags);
  } else {
    gemm_glds<512, 64, 64><<<dim3(N / 64, R / 64), 256, 0, stream>>>(A, Wt, bias, res, C, N, flags);
  }
}

// ---------------- host launcher ----------------
extern "C" void kernel_launch(void* const* d_in, const int* in_sizes, int n_in,
                              void* d_out, int out_size, void* d_ws, size_t ws_size,
                              hipStream_t stream){
  const float* xc      = (const float*)d_in[0];
  const float* zc_in   = (const float*)d_in[1];
  const float* xt      = (const float*)d_in[2];
  const float* zt_in   = (const float*)d_in[3];
  const float* sa_wqkv = (const float*)d_in[4];
  const float* sa_wo   = (const float*)d_in[5];
  const float* sa_ln1  = (const float*)d_in[6];
  const float* sa_ln2  = (const float*)d_in[7];
  const float* sa_w1   = (const float*)d_in[8];
  const float* sa_b1   = (const float*)d_in[9];
  const float* sa_w2   = (const float*)d_in[10];
  const float* sa_b2   = (const float*)d_in[11];
  const float* ca_wq   = (const float*)d_in[12];
  const float* ca_wkv  = (const float*)d_in[13];
  const float* ca_wo   = (const float*)d_in[14];
  const float* ca_lnq  = (const float*)d_in[15];
  const float* ca_lnkv = (const float*)d_in[16];
  const float* ca_ln2  = (const float*)d_in[17];
  const float* ca_w1   = (const float*)d_in[18];
  const float* ca_b1   = (const float*)d_in[19];
  const float* ca_w2   = (const float*)d_in[20];
  const float* ca_b2   = (const float*)d_in[21];

  if (ws_size < (size_t)WS_FLOATS * sizeof(float)) return;
  float* ws    = (float*)d_ws;
  float* zc    = ws + ZC_OFF;
  unsigned short* hb16 = (unsigned short*)(ws + H_OFF);
  float* qkvb  = ws + QKV_OFF;   // aliased: bf16 qkv / fp32 CA kv / bf16 ffn-mid
  unsigned short* qkv16 = (unsigned short*)qkvb;
  unsigned short* wt    = (unsigned short*)(ws + WT_OFF);
  float* fb    = ws + FB_OFF;
  float* qb    = ws + Q_OFF;
  unsigned short* ob16 = (unsigned short*)(ws + O_OFF);
  int*   idxb  = (int*)(ws + IDX_OFF);
  float* maskb = ws + MASK_OFF;
  float* zt    = (float*)d_out;

  // ---- weight prep (transpose + gamma row-scale) ----
  TTable tt;
  for (int l = 0; l < LAYERS; l++){
    int b = l * WT_LAYER, i = l * 9;
    tt.e[i + 0] = { sa_wqkv + (size_t)l * 256 * 768, sa_ln1  + l * 512, b + WT_QKV,  256, 768 };
    tt.e[i + 1] = { sa_wo   + (size_t)l * 256 * 256, nullptr,           b + WT_WO,   256, 256 };
    tt.e[i + 2] = { sa_w1   + (size_t)l * 256 * 512, sa_ln2  + l * 512, b + WT_W1,   256, 512 };
    tt.e[i + 3] = { sa_w2   + (size_t)l * 512 * 256, nullptr,           b + WT_W2,   512, 256 };
    tt.e[i + 4] = { ca_wq   + (size_t)l * 256 * 256, ca_lnq  + l * 512, b + WT_CWQ,  256, 256 };
    tt.e[i + 5] = { ca_wkv  + (size_t)l * 256 * 512, ca_lnkv + l * 512, b + WT_CWKV, 256, 512 };
    tt.e[i + 6] = { ca_wo   + (size_t)l * 256 * 256, nullptr,           b + WT_CWO,  256, 256 };
    tt.e[i + 7] = { ca_w1   + (size_t)l * 256 * 512, ca_ln2  + l * 512, b + WT_CW1,  256, 512 };
    tt.e[i + 8] = { ca_w2   + (size_t)l * 512 * 256, nullptr,           b + WT_CW2,  512, 256 };
  }
  wprep_kernel<<<dim3(24, 16, 18), dim3(32, 8), 0, stream>>>(tt, wt);

  // ---- beta fold into biases (parallel) ----
  BTable bt;
  for (int l = 0; l < LAYERS; l++){
    int fo = l * FB_LAYER, i = l * 5;
    bt.e[i + 0] = { sa_wqkv + (size_t)l * 256 * 768, sa_ln1  + l * 512 + 256, nullptr,        fo + FB_QKV, 768 };
    bt.e[i + 1] = { sa_w1   + (size_t)l * 256 * 512, sa_ln2  + l * 512 + 256, sa_b1 + l * FF, fo + FB_W1,  512 };
    bt.e[i + 2] = { ca_wkv  + (size_t)l * 256 * 512, ca_lnkv + l * 512 + 256, nullptr,        fo + FB_WKV, 512 };
    bt.e[i + 3] = { ca_wq   + (size_t)l * 256 * 256, ca_lnq  + l * 512 + 256, nullptr,        fo + FB_WQ,  256 };
    bt.e[i + 4] = { ca_w1   + (size_t)l * 256 * 512, ca_ln2  + l * 512 + 256, ca_b1 + l * FF, fo + FB_CW1, 512 };
  }
  bfold_kernel<<<dim3(10, 12), 256, 0, stream>>>(bt, fb);

  nn_idx_kernel<<<(MB * NTGT) / 256, 256, 0, stream>>>(xc, xt, idxb, maskb);

  for (int l = 0; l < LAYERS; l++){
    const unsigned short* wl = wt + (size_t)l * WT_LAYER;
    const float* fl = fb + (size_t)l * FB_LAYER;
    const float* zc_src = (l == 0) ? zc_in : zc;
    const float* zt_src = (l == 0) ? zt_in : zt;

    // ---------- self-attention block on zc ----------
    ln_norm<<<RC / 4, 256, 0, stream>>>(zc_src, hb16, RC);
    launch_gemm(hb16, wl + WT_QKV, fl + FB_QKV, nullptr, qkv16, RC, 256, 768, 1 | 8, stream);
    sa_attn_mfma<<<dim3(NCTX / 64, NHEAD, MB), 256, 0, stream>>>(qkv16, ob16);
    launch_gemm(ob16, wl + WT_WO, nullptr, zc_src, zc, RC, 256, 256, 4, stream);
    ln_norm<<<RC / 4, 256, 0, stream>>>(zc, hb16, RC);
    launch_gemm(hb16, wl + WT_W1, fl + FB_W1, nullptr, qkv16, RC, 256, 512, 1 | 2 | 8, stream);
    launch_gemm(qkv16, wl + WT_W2, sa_b2 + l * DMODEL, zc, zc, RC, 512, 256, 1 | 4, stream);

    // ---------- cross-attention block on zt ----------
    ln_norm<<<RC / 4, 256, 0, stream>>>(zc, hb16, RC);
    launch_gemm(hb16, wl + WT_CWKV, fl + FB_WKV, nullptr, qkvb, RC, 256, 512, 1, stream);
    ln_norm<<<RT / 4, 256, 0, stream>>>(zt_src, hb16, RT);
    launch_gemm(hb16, wl + WT_CWQ, fl + FB_WQ, nullptr, qb, RT, 256, 256, 1, stream);
    ca_attn_kernel<<<RT, 256, 0, stream>>>(qb, qkvb, idxb, maskb, ob16);
    launch_gemm(ob16, wl + WT_CWO, nullptr, zt_src, zt, RT, 256, 256, 4, stream);
    ln_norm<<<RT / 4, 256, 0, stream>>>(zt, hb16, RT);
    launch_gemm(hb16, wl + WT_CW1, fl + FB_CW1, nullptr, qkv16, RT, 256, 512, 1 | 2 | 8, stream);
    launch_gemm(qkv16, wl + WT_CW2, ca_b2 + l * DMODEL, zt, zt, RT, 512, 256, 1 | 4, stream);
  }
}

// Round 11
// 396.315 us; speedup vs baseline: 1.6619x; 1.0093x over previous
//
#include <hip/hip_runtime.h>
#include <math.h>

// ---------------- problem constants ----------------
#define LAYERS 2
#define DMODEL 256
#define NHEAD  8
#define DHEAD  32
#define FF     512
#define KNB    9
#define MB     4
#define G1D    40
#define G2D    40
#define NTGT   2048
#define NCTX   1600          // G1D*G2D
#define RC     (MB*NCTX)     // 6400 grid rows
#define RT     (MB*NTGT)     // 8192 target rows

typedef __attribute__((ext_vector_type(8))) short short8;   // 8 bf16 (4 VGPRs)
typedef __attribute__((ext_vector_type(4))) float f32x4;    // mfma C/D

#if __has_builtin(__builtin_amdgcn_exp2f)
#define EXP2(x) __builtin_amdgcn_exp2f(x)
#else
#define EXP2(x) exp2f(x)
#endif
#define L2E 1.4426950408889634f
#define ATTN_SCALE 0.17677669529663687f   // 1/sqrt(32)

// ---------------- workspace layout (float offsets) ----------------
#define ZC_OFF    0
#define H_OFF     1638400                      // bf16 LN output
#define QKV_OFF   (H_OFF + 2097152)
#define WT_OFF    (QKV_OFF + 3400000)          // bf16 wT (tail of QKV region)
#define FB_OFF    (QKV_OFF + 4500000)          // folded biases
#define Q_OFF     (QKV_OFF + 4915200)
#define O_OFF     (Q_OFF + 2097152)
#define IDX_OFF   (O_OFF + 2097152)
#define MASK_OFF  (IDX_OFF + 73728)
#define WS_FLOATS (MASK_OFF + 73728)

// per-layer wT offsets (shorts)
#define WT_LAYER   1048576
#define WT_QKV     0
#define WT_WO      196608
#define WT_W1      262144
#define WT_W2      393216
#define WT_CWQ     524288
#define WT_CWKV    589824
#define WT_CWO     720896
#define WT_CW1     786432
#define WT_CW2     917504
// per-layer folded-bias offsets (floats), layer stride 2560
#define FB_LAYER   2560
#define FB_QKV     0
#define FB_W1      768
#define FB_WKV     1280
#define FB_WQ      1792
#define FB_CW1     2048

static __device__ __forceinline__ float gelu_f(float x){
  float t = tanhf(0.7978845608028654f * (x + 0.044715f * x * x * x));
  return 0.5f * x * (1.0f + t);
}
static __device__ __forceinline__ unsigned int bf16_rne(float x){
  unsigned int u = __float_as_uint(x);
  return (u + 0x7fffu + ((u >> 16) & 1u)) >> 16;
}
static __device__ __forceinline__ unsigned int pack_bf16x2(float lo, float hi){
  return bf16_rne(lo) | (bf16_rne(hi) << 16);
}

// ------ weight prep: fp32 [K][N] -> bf16 [N][K], row-scaled by gamma, col-scaled -----
// nse/nsc: output cols n < nse get multiplied by nsc (folds attn scale into Q weights).
struct TDesc { const float* src; const float* gamma; int dstoff; int K; int N; int nse; float nsc; };
struct TTable { TDesc e[18]; };

__global__ __launch_bounds__(256)
void wprep_kernel(TTable t, unsigned short* __restrict__ wt){
  TDesc d = t.e[blockIdx.z];
  int n0 = blockIdx.x * 32, k0 = blockIdx.y * 32;
  if (n0 >= d.N || k0 >= d.K) return;
  __shared__ float tile[32][33];
  int tx = threadIdx.x, ty = threadIdx.y;
  float csc = (n0 + tx < d.nse) ? d.nsc : 1.0f;
  #pragma unroll
  for (int j = 0; j < 4; j++){
    int k = k0 + ty * 4 + j;
    float v = d.src[(size_t)k * d.N + n0 + tx];
    if (d.gamma) v *= d.gamma[k];
    tile[ty * 4 + j][tx] = v * csc;
  }
  __syncthreads();
  #pragma unroll
  for (int j = 0; j < 4; j++)
    wt[(size_t)d.dstoff + (size_t)(n0 + ty * 4 + j) * d.K + k0 + tx] =
        (unsigned short)bf16_rne(tile[tx][ty * 4 + j]);
}

// ---------------- bias fold (parallel): fb[n] = (base[n] + sum_k beta[k]*W[k][n])*sc -
struct BDesc { const float* W; const float* beta; const float* base; int outoff; int N; int nse; float nsc; };
struct BTable { BDesc e[10]; };

__global__ __launch_bounds__(256)
void bfold_kernel(BTable t, float* __restrict__ fb){
  BDesc d = t.e[blockIdx.x];
  int n = blockIdx.y * 64 + (threadIdx.x >> 2);
  int q = threadIdx.x & 3;
  if (n >= d.N) return;
  float s = 0.f;
  #pragma unroll 4
  for (int k = q * 64; k < q * 64 + 64; k++)
    s += d.beta[k] * d.W[(size_t)k * d.N + n];
  s += __shfl_xor(s, 1);
  s += __shfl_xor(s, 2);
  if (q == 0){
    float r = s + (d.base ? d.base[n] : 0.f);
    if (n < d.nse) r *= d.nsc;
    fb[d.outoff + n] = r;
  }
}

// ---------------- nearest-grid-neighbour index/mask precompute ----------------
__global__ void nn_idx_kernel(const float* __restrict__ xc, const float* __restrict__ xt,
                              int* __restrict__ idx, float* __restrict__ mask){
  int g = blockIdx.x * blockDim.x + threadIdx.x;
  if (g >= MB * NTGT) return;
  int m = g >> 11;
  float x0 = xt[(size_t)g * 2 + 0];
  float x1 = xt[(size_t)g * 2 + 1];
  const float* xcm = xc + (size_t)m * G1D * G2D * 2;
  int n0 = 0; float b0 = 1e30f;
  for (int i = 0; i < G1D; i++){
    float d = fabsf(x0 - xcm[i * (G2D * 2)]);
    if (d < b0){ b0 = d; n0 = i; }
  }
  int n1 = 0; float b1 = 1e30f;
  for (int j = 0; j < G2D; j++){
    float d = fabsf(x1 - xcm[j * 2 + 1]);
    if (d < b1){ b1 = d; n1 = j; }
  }
  #pragma unroll
  for (int a = 0; a < 3; a++){
    int r0 = n0 + a - 1;
    bool v0 = (r0 >= 0) && (r0 < G1D);
    int i0 = min(max(r0, 0), G1D - 1);
    #pragma unroll
    for (int b = 0; b < 3; b++){
      int r1 = n1 + b - 1;
      bool v1 = (r1 >= 0) && (r1 < G2D);
      int i1 = min(max(r1, 0), G2D - 1);
      idx [(size_t)g * KNB + a * 3 + b] = i0 * G2D + i1;
      mask[(size_t)g * KNB + a * 3 + b] = (v0 && v1) ? 1.0f : 0.0f;
    }
  }
}

// ---------------- LayerNorm normalize-only (affine folded into wT/bias), bf16 out ----
__global__ __launch_bounds__(256)
void ln_norm(const float* __restrict__ x, unsigned short* __restrict__ y, int rows){
  int gw   = blockIdx.x * 4 + (threadIdx.x >> 6);
  int lane = threadIdx.x & 63;
  if (gw >= rows) return;
  const float* xr = x + (size_t)gw * DMODEL;
  int d0 = lane * 4;
  float4 xv = *(const float4*)(xr + d0);
  float s = xv.x + xv.y + xv.z + xv.w;
  #pragma unroll
  for (int off = 32; off > 0; off >>= 1) s += __shfl_xor(s, off);
  float mu = s * (1.0f / DMODEL);
  float dx0 = xv.x - mu, dx1 = xv.y - mu, dx2 = xv.z - mu, dx3 = xv.w - mu;
  float v = dx0*dx0 + dx1*dx1 + dx2*dx2 + dx3*dx3;
  #pragma unroll
  for (int off = 32; off > 0; off >>= 1) v += __shfl_xor(v, off);
  float rs = rsqrtf(v * (1.0f / DMODEL) + 1e-5f);
  uint2 w;
  w.x = pack_bf16x2(dx0 * rs, dx1 * rs);
  w.y = pack_bf16x2(dx2 * rs, dx3 * rs);
  *(uint2*)(y + (size_t)gw * DMODEL + d0) = w;
}

// ================= MFMA GEMM, templated tile (MTxNT), BK=64 dbuf, glds staging ======
// A bf16 [R][K], Wt bf16 [N][K]. Linear LDS dest + inverse-swizzled global source +
// swizzled ds_read (rule #21; verified r9). Tiles: 64x64 (N<=512) / 64x128 (N=768).
// flags: 1=bias, 2=gelu, 4=residual(fp32), 8=bf16 out

template<int ROWS>
static __device__ __forceinline__ void stage_glds(const unsigned short* __restrict__ src,
                                                  int Ksrc, unsigned short* lds,
                                                  int wave, int lane){
  #pragma unroll
  for (int j = 0; j < ROWS / 32; j++){
    int ublk = (j * 4 + wave) * 64;          // wave-uniform first 16B-unit
    int u    = ublk + lane;
    int row  = u >> 3;                       // 8 units (128B) per row
    int unit = (u & 7) ^ (row & 7);          // source pre-swizzle
    __builtin_amdgcn_global_load_lds(
        (const __attribute__((address_space(1))) void*)(src + (size_t)row * Ksrc + unit * 8),
        (__attribute__((address_space(3))) void*)(lds + (size_t)ublk * 8),
        16, 0, 0);
  }
}

template<int K, int MT, int NT>
__global__ __launch_bounds__(256)
void gemm_glds(const unsigned short* __restrict__ A, const unsigned short* __restrict__ Wt,
               const float* __restrict__ bias, const float* __restrict__ res,
               void* __restrict__ C, int N, int flags){
  const int MFR = MT / 32, NFR = NT / 32;    // 16x16 frags per wave
  __shared__ unsigned short Als[2][MT * 64];
  __shared__ unsigned short Bls[2][NT * 64];
  int tid = threadIdx.x;
  int wave = tid >> 6, lane = tid & 63;
  int wm = wave >> 1, wn = wave & 1;
  int l16 = lane & 15, grp = lane >> 4;
  int r0 = blockIdx.y * MT, c0 = blockIdx.x * NT;

  const unsigned short* Ag = A  + (size_t)r0 * K;
  const unsigned short* Bg = Wt + (size_t)c0 * K;
  const int nch = K >> 6;

  stage_glds<MT>(Ag, K, Als[0], wave, lane);
  stage_glds<NT>(Bg, K, Bls[0], wave, lane);

  f32x4 acc[MFR][NFR];
  #pragma unroll
  for (int m = 0; m < MFR; m++)
    #pragma unroll
    for (int n = 0; n < NFR; n++) acc[m][n] = (f32x4){0.f, 0.f, 0.f, 0.f};

  #pragma unroll
  for (int ch = 0; ch < nch; ch++){
    int b = ch & 1;
    __syncthreads();
    if (ch + 1 < nch){
      stage_glds<MT>(Ag + (ch + 1) * 64, K, Als[b ^ 1], wave, lane);
      stage_glds<NT>(Bg + (ch + 1) * 64, K, Bls[b ^ 1], wave, lane);
    }
    const unsigned short* Ab = Als[b];
    const unsigned short* Bb = Bls[b];
    #pragma unroll
    for (int kk = 0; kk < 2; kk++){
      short8 af[MFR], bfr[NFR];
      #pragma unroll
      for (int m = 0; m < MFR; m++){
        int row = wm * (MT / 2) + m * 16 + l16;
        int unit = (kk * 4 + grp) ^ (row & 7);
        af[m] = *(const short8*)(Ab + row * 64 + unit * 8);
      }
      #pragma unroll
      for (int n = 0; n < NFR; n++){
        int row = wn * (NT / 2) + n * 16 + l16;
        int unit = (kk * 4 + grp) ^ (row & 7);
        bfr[n] = *(const short8*)(Bb + row * 64 + unit * 8);
      }
      #pragma unroll
      for (int m = 0; m < MFR; m++)
        #pragma unroll
        for (int n = 0; n < NFR; n++)
          acc[m][n] = __builtin_amdgcn_mfma_f32_16x16x32_bf16(af[m], bfr[n], acc[m][n], 0, 0, 0);
    }
  }

  #pragma unroll
  for (int n = 0; n < NFR; n++){
    int gc = c0 + wn * (NT / 2) + n * 16 + l16;
    float bv = (flags & 1) ? bias[gc] : 0.f;
    #pragma unroll
    for (int m = 0; m < MFR; m++){
      int grb = r0 + wm * (MT / 2) + m * 16 + grp * 4;
      #pragma unroll
      for (int r = 0; r < 4; r++){
        float v = acc[m][n][r] + bv;
        if (flags & 2) v = gelu_f(v);
        if (flags & 4) v += res[(size_t)(grb + r) * N + gc];
        if (flags & 8) ((unsigned short*)C)[(size_t)(grb + r) * N + gc] = (unsigned short)bf16_rne(v);
        else           ((float*)C)[(size_t)(grb + r) * N + gc] = v;
      }
    }
  }
}

// ------- self-attention: bf16 MFMA flash (r4 structure; Q pre-scaled by s*log2e ------
// at wprep, so softmax is mul-free in exp2 domain). VSTR 70: V-transpose stores
// spread over all 32 banks (72 collapsed scol groups onto 8 banks -> 8-way).
#define KSTR 40
#define VSTR 70
#define PSTR 72
__global__ __launch_bounds__(256)
void sa_attn_mfma(const unsigned short* __restrict__ qkv, unsigned short* __restrict__ ob){
  int m = blockIdx.z, h = blockIdx.y;
  int tid  = threadIdx.x;
  int wave = tid >> 6, lane = tid & 63;
  int qr = lane & 15, grp = lane >> 4;
  int q0 = blockIdx.x * 64 + wave * 16;

  __shared__ unsigned short Kls[2][64 * KSTR];
  __shared__ unsigned short Vls[2][32 * VSTR];
  __shared__ unsigned short Pls[4][16 * PSTR];
  unsigned short* Pw = Pls[wave];

  short8 qf = *(const short8*)(qkv + ((size_t)(m * NCTX + q0 + qr)) * 768 + h * 32 + grp * 8);

  int skey = tid >> 2;
  int scol = (tid & 3) * 8;
  const unsigned short* kbase = qkv + (size_t)m * NCTX * 768 + 256 + h * 32 + scol;

  uint4 kreg = *(const uint4*)(kbase + (size_t)skey * 768);
  uint4 vreg = *(const uint4*)(kbase + (size_t)skey * 768 + 256);

  float mq = -1e30f, lq = 0.0f;
  f32x4 acc0 = {0.f, 0.f, 0.f, 0.f};
  f32x4 acc1 = {0.f, 0.f, 0.f, 0.f};

  {
    *(uint4*)&Kls[0][skey * KSTR + scol] = kreg;
    unsigned int vv[4] = {vreg.x, vreg.y, vreg.z, vreg.w};
    #pragma unroll
    for (int j = 0; j < 4; j++){
      Vls[0][(scol + 2 * j    ) * VSTR + skey] = (unsigned short)(vv[j] & 0xffffu);
      Vls[0][(scol + 2 * j + 1) * VSTR + skey] = (unsigned short)(vv[j] >> 16);
    }
  }

  for (int kt = 0; kt < NCTX / 64; kt++){
    int b = kt & 1;
    __syncthreads();
    if (kt + 1 < NCTX / 64){
      kreg = *(const uint4*)(kbase + (size_t)((kt + 1) * 64 + skey) * 768);
      vreg = *(const uint4*)(kbase + (size_t)((kt + 1) * 64 + skey) * 768 + 256);
    }

    f32x4 s0 = {0.f,0.f,0.f,0.f}, s1 = {0.f,0.f,0.f,0.f};
    f32x4 s2 = {0.f,0.f,0.f,0.f}, s3 = {0.f,0.f,0.f,0.f};
    {
      const short8 k0 = *(const short8*)&Kls[b][( 0 + qr) * KSTR + grp * 8];
      const short8 k1 = *(const short8*)&Kls[b][(16 + qr) * KSTR + grp * 8];
      const short8 k2 = *(const short8*)&Kls[b][(32 + qr) * KSTR + grp * 8];
      const short8 k3 = *(const short8*)&Kls[b][(48 + qr) * KSTR + grp * 8];
      s0 = __builtin_amdgcn_mfma_f32_16x16x32_bf16(k0, qf, s0, 0, 0, 0);
      s1 = __builtin_amdgcn_mfma_f32_16x16x32_bf16(k1, qf, s1, 0, 0, 0);
      s2 = __builtin_amdgcn_mfma_f32_16x16x32_bf16(k2, qf, s2, 0, 0, 0);
      s3 = __builtin_amdgcn_mfma_f32_16x16x32_bf16(k3, qf, s3, 0, 0, 0);
    }

    // scores already in exp2 domain (Q pre-scaled by scale*log2e at wprep)
    float sc[4][4];
    #pragma unroll
    for (int r = 0; r < 4; r++){
      sc[0][r] = s0[r]; sc[1][r] = s1[r]; sc[2][r] = s2[r]; sc[3][r] = s3[r];
    }
    float tm = sc[0][0];
    #pragma unroll
    for (int kb = 0; kb < 4; kb++)
      #pragma unroll
      for (int r = 0; r < 4; r++) tm = fmaxf(tm, sc[kb][r]);
    tm = fmaxf(tm, __shfl_xor(tm, 16));
    tm = fmaxf(tm, __shfl_xor(tm, 32));
    float mn = fmaxf(mq, tm);
    float corr = EXP2(mq - mn);
    float ts = 0.f;
    float p[4][4];
    #pragma unroll
    for (int kb = 0; kb < 4; kb++)
      #pragma unroll
      for (int r = 0; r < 4; r++){
        float pv = EXP2(sc[kb][r] - mn);
        p[kb][r] = pv; ts += pv;
      }
    ts += __shfl_xor(ts, 16);
    ts += __shfl_xor(ts, 32);
    lq = lq * corr + ts;
    mq = mn;
    #pragma unroll
    for (int r = 0; r < 4; r++){ acc0[r] *= corr; acc1[r] *= corr; }

    #pragma unroll
    for (int kb = 0; kb < 4; kb++){
      *(unsigned int*)&Pw[qr * PSTR + kb * 16 + grp * 4]     = pack_bf16x2(p[kb][0], p[kb][1]);
      *(unsigned int*)&Pw[qr * PSTR + kb * 16 + grp * 4 + 2] = pack_bf16x2(p[kb][2], p[kb][3]);
    }

    #pragma unroll
    for (int hh = 0; hh < 2; hh++){
      const short8 pf = *(const short8*)&Pw[qr * PSTR + hh * 32 + grp * 8];
      const short8 v0 = *(const short8*)&Vls[b][( 0 + qr) * VSTR + hh * 32 + grp * 8];
      const short8 v1 = *(const short8*)&Vls[b][(16 + qr) * VSTR + hh * 32 + grp * 8];
      acc0 = __builtin_amdgcn_mfma_f32_16x16x32_bf16(v0, pf, acc0, 0, 0, 0);
      acc1 = __builtin_amdgcn_mfma_f32_16x16x32_bf16(v1, pf, acc1, 0, 0, 0);
    }

    if (kt + 1 < NCTX / 64){
      *(uint4*)&Kls[b ^ 1][skey * KSTR + scol] = kreg;
      unsigned int vv[4] = {vreg.x, vreg.y, vreg.z, vreg.w};
      #pragma unroll
      for (int j = 0; j < 4; j++){
        Vls[b ^ 1][(scol + 2 * j    ) * VSTR + skey] = (unsigned short)(vv[j] & 0xffffu);
        Vls[b ^ 1][(scol + 2 * j + 1) * VSTR + skey] = (unsigned short)(vv[j] >> 16);
      }
    }
  }

  float inv = 1.0f / lq;
  unsigned short* op = ob + ((size_t)(m * NCTX + q0 + qr)) * DMODEL + h * DHEAD;
  uint2 o16a, o16b;
  o16a.x = pack_bf16x2(acc0[0] * inv, acc0[1] * inv);
  o16a.y = pack_bf16x2(acc0[2] * inv, acc0[3] * inv);
  o16b.x = pack_bf16x2(acc1[0] * inv, acc1[1] * inv);
  o16b.y = pack_bf16x2(acc1[2] * inv, acc1[3] * inv);
  *(uint2*)(op + grp * 4)      = o16a;
  *(uint2*)(op + 16 + grp * 4) = o16b;
}

// ------- cross-attention over 9 gathered neighbours (q pre-scaled at wprep) ---------
__global__ __launch_bounds__(256)
void ca_attn_kernel(const float* __restrict__ qb, const float* __restrict__ kv,
                    const int* __restrict__ idx, const float* __restrict__ mask,
                    unsigned short* __restrict__ ob){
  int g = blockIdx.x;
  int m = g >> 11;
  int tid = threadIdx.x;
  float q = qb[(size_t)g * DMODEL + tid];
  float s[KNB];
  int rws[KNB];
  #pragma unroll
  for (int k = 0; k < KNB; k++){
    int row = idx[(size_t)g * KNB + k];
    rws[k] = row;
    float p = q * kv[((size_t)(m * NCTX + row)) * 512 + tid];
    #pragma unroll
    for (int off = 16; off > 0; off >>= 1) p += __shfl_xor(p, off, 32);
    s[k] = (mask[(size_t)g * KNB + k] > 0.5f) ? p : -1e30f;
  }
  float sm = s[0];
  #pragma unroll
  for (int k = 1; k < KNB; k++) sm = fmaxf(sm, s[k]);
  float den = 0.f, w[KNB];
  #pragma unroll
  for (int k = 0; k < KNB; k++){ w[k] = __expf(s[k] - sm); den += w[k]; }
  float inv = 1.0f / den;
  float o = 0.f;
  #pragma unroll
  for (int k = 0; k < KNB; k++)
    o += w[k] * kv[((size_t)(m * NCTX + rws[k])) * 512 + 256 + tid];
  ob[(size_t)g * DMODEL + tid] = (unsigned short)bf16_rne(o * inv);
}

// ---------------- host launch helper ----------------
static inline void launch_gemm(const unsigned short* A, const unsigned short* Wt,
                               const float* bias, const float* res, void* C,
                               int R, int K, int N, int flags, hipStream_t stream){
  if (N == 768){
    gemm_glds<256, 64, 128><<<dim3(N / 128, R / 64), 256, 0, stream>>>(A, Wt, bias, res, C, N, flags);
  } else if (K == 256){
    gemm_glds<256, 64, 64><<<dim3(N / 64, R / 64), 256, 0, stream>>>(A, Wt, bias, res, C, N, flags);
  } else {
    gemm_glds<512, 64, 64><<<dim3(N / 64, R / 64), 256, 0, stream>>>(A, Wt, bias, res, C, N, flags);
  }
}

// ---------------- host launcher ----------------
extern "C" void kernel_launch(void* const* d_in, const int* in_sizes, int n_in,
                              void* d_out, int out_size, void* d_ws, size_t ws_size,
                              hipStream_t stream){
  const float* xc      = (const float*)d_in[0];
  const float* zc_in   = (const float*)d_in[1];
  const float* xt      = (const float*)d_in[2];
  const float* zt_in   = (const float*)d_in[3];
  const float* sa_wqkv = (const float*)d_in[4];
  const float* sa_wo   = (const float*)d_in[5];
  const float* sa_ln1  = (const float*)d_in[6];
  const float* sa_ln2  = (const float*)d_in[7];
  const float* sa_w1   = (const float*)d_in[8];
  const float* sa_b1   = (const float*)d_in[9];
  const float* sa_w2   = (const float*)d_in[10];
  const float* sa_b2   = (const float*)d_in[11];
  const float* ca_wq   = (const float*)d_in[12];
  const float* ca_wkv  = (const float*)d_in[13];
  const float* ca_wo   = (const float*)d_in[14];
  const float* ca_lnq  = (const float*)d_in[15];
  const float* ca_lnkv = (const float*)d_in[16];
  const float* ca_ln2  = (const float*)d_in[17];
  const float* ca_w1   = (const float*)d_in[18];
  const float* ca_b1   = (const float*)d_in[19];
  const float* ca_w2   = (const float*)d_in[20];
  const float* ca_b2   = (const float*)d_in[21];

  if (ws_size < (size_t)WS_FLOATS * sizeof(float)) return;
  float* ws    = (float*)d_ws;
  float* zc    = ws + ZC_OFF;
  unsigned short* hb16 = (unsigned short*)(ws + H_OFF);
  float* qkvb  = ws + QKV_OFF;   // aliased: bf16 qkv / fp32 CA kv / bf16 ffn-mid
  unsigned short* qkv16 = (unsigned short*)qkvb;
  unsigned short* wt    = (unsigned short*)(ws + WT_OFF);
  float* fb    = ws + FB_OFF;
  float* qb    = ws + Q_OFF;
  unsigned short* ob16 = (unsigned short*)(ws + O_OFF);
  int*   idxb  = (int*)(ws + IDX_OFF);
  float* maskb = ws + MASK_OFF;
  float* zt    = (float*)d_out;

  const float QSC = ATTN_SCALE * L2E;   // folded into sa Q (exp2-domain softmax)

  // ---- weight prep (transpose + gamma row-scale + Q col-scale) ----
  TTable tt;
  for (int l = 0; l < LAYERS; l++){
    int b = l * WT_LAYER, i = l * 9;
    tt.e[i + 0] = { sa_wqkv + (size_t)l * 256 * 768, sa_ln1  + l * 512, b + WT_QKV,  256, 768, 256, QSC };
    tt.e[i + 1] = { sa_wo   + (size_t)l * 256 * 256, nullptr,           b + WT_WO,   256, 256, 0, 1.f };
    tt.e[i + 2] = { sa_w1   + (size_t)l * 256 * 512, sa_ln2  + l * 512, b + WT_W1,   256, 512, 0, 1.f };
    tt.e[i + 3] = { sa_w2   + (size_t)l * 512 * 256, nullptr,           b + WT_W2,   512, 256, 0, 1.f };
    tt.e[i + 4] = { ca_wq   + (size_t)l * 256 * 256, ca_lnq  + l * 512, b + WT_CWQ,  256, 256, 256, ATTN_SCALE };
    tt.e[i + 5] = { ca_wkv  + (size_t)l * 256 * 512, ca_lnkv + l * 512, b + WT_CWKV, 256, 512, 0, 1.f };
    tt.e[i + 6] = { ca_wo   + (size_t)l * 256 * 256, nullptr,           b + WT_CWO,  256, 256, 0, 1.f };
    tt.e[i + 7] = { ca_w1   + (size_t)l * 256 * 512, ca_ln2  + l * 512, b + WT_CW1,  256, 512, 0, 1.f };
    tt.e[i + 8] = { ca_w2   + (size_t)l * 512 * 256, nullptr,           b + WT_CW2,  512, 256, 0, 1.f };
  }
  wprep_kernel<<<dim3(24, 16, 18), dim3(32, 8), 0, stream>>>(tt, wt);

  // ---- beta fold into biases (parallel; Q-part scaled to match) ----
  BTable bt;
  for (int l = 0; l < LAYERS; l++){
    int fo = l * FB_LAYER, i = l * 5;
    bt.e[i + 0] = { sa_wqkv + (size_t)l * 256 * 768, sa_ln1  + l * 512 + 256, nullptr,        fo + FB_QKV, 768, 256, QSC };
    bt.e[i + 1] = { sa_w1   + (size_t)l * 256 * 512, sa_ln2  + l * 512 + 256, sa_b1 + l * FF, fo + FB_W1,  512, 0, 1.f };
    bt.e[i + 2] = { ca_wkv  + (size_t)l * 256 * 512, ca_lnkv + l * 512 + 256, nullptr,        fo + FB_WKV, 512, 0, 1.f };
    bt.e[i + 3] = { ca_wq   + (size_t)l * 256 * 256, ca_lnq  + l * 512 + 256, nullptr,        fo + FB_WQ,  256, 256, ATTN_SCALE };
    bt.e[i + 4] = { ca_w1   + (size_t)l * 256 * 512, ca_ln2  + l * 512 + 256, ca_b1 + l * FF, fo + FB_CW1, 512, 0, 1.f };
  }
  bfold_kernel<<<dim3(10, 12), 256, 0, stream>>>(bt, fb);

  nn_idx_kernel<<<(MB * NTGT) / 256, 256, 0, stream>>>(xc, xt, idxb, maskb);

  for (int l = 0; l < LAYERS; l++){
    const unsigned short* wl = wt + (size_t)l * WT_LAYER;
    const float* fl = fb + (size_t)l * FB_LAYER;
    const float* zc_src = (l == 0) ? zc_in : zc;
    const float* zt_src = (l == 0) ? zt_in : zt;

    // ---------- self-attention block on zc ----------
    ln_norm<<<RC / 4, 256, 0, stream>>>(zc_src, hb16, RC);
    launch_gemm(hb16, wl + WT_QKV, fl + FB_QKV, nullptr, qkv16, RC, 256, 768, 1 | 8, stream);
    sa_attn_mfma<<<dim3(NCTX / 64, NHEAD, MB), 256, 0, stream>>>(qkv16, ob16);
    launch_gemm(ob16, wl + WT_WO, nullptr, zc_src, zc, RC, 256, 256, 4, stream);
    ln_norm<<<RC / 4, 256, 0, stream>>>(zc, hb16, RC);
    launch_gemm(hb16, wl + WT_W1, fl + FB_W1, nullptr, qkv16, RC, 256, 512, 1 | 2 | 8, stream);
    launch_gemm(qkv16, wl + WT_W2, sa_b2 + l * DMODEL, zc, zc, RC, 512, 256, 1 | 4, stream);

    // ---------- cross-attention block on zt ----------
    ln_norm<<<RC / 4, 256, 0, stream>>>(zc, hb16, RC);
    launch_gemm(hb16, wl + WT_CWKV, fl + FB_WKV, nullptr, qkvb, RC, 256, 512, 1, stream);
    ln_norm<<<RT / 4, 256, 0, stream>>>(zt_src, hb16, RT);
    launch_gemm(hb16, wl + WT_CWQ, fl + FB_WQ, nullptr, qb, RT, 256, 256, 1, stream);
    ca_attn_kernel<<<RT, 256, 0, stream>>>(qb, qkvb, idxb, maskb, ob16);
    launch_gemm(ob16, wl + WT_CWO, nullptr, zt_src, zt, RT, 256, 256, 4, stream);
    ln_norm<<<RT / 4, 256, 0, stream>>>(zt, hb16, RT);
    launch_gemm(hb16, wl + WT_CW1, fl + FB_CW1, nullptr, qkv16, RT, 256, 512, 1 | 2 | 8, stream);
    launch_gemm(qkv16, wl + WT_CW2, ca_b2 + l * DMODEL, zt, zt, RT, 512, 256, 1 | 4, stream);
  }
}